// Round 1
// baseline (109.029 us; speedup 1.0000x reference)
//
#include <hip/hip_runtime.h>
#include <math.h>

#ifndef M_PI
#define M_PI 3.14159265358979323846
#endif

#define IMGW 1024
#define SIDX(m,n) ((m)*9 - ((m)*((m)-1))/2 + ((n)-(m)))

// One Jacobi rotation in the (P,Q) plane on a full 6x6 symmetric matrix A,
// accumulating eigenvectors into V (columns). P,Q compile-time -> registers.
template<int P, int Q>
__device__ __forceinline__ void jrot(double (&A)[6][6], double (&V)[6][6]) {
    double apq = A[P][Q];
    if (fabs(apq) > 1e-300) {
        double app = A[P][P], aqq = A[Q][Q];
        double tau = (aqq - app) / (2.0 * apq);
        double t = copysign(1.0, tau) / (fabs(tau) + sqrt(1.0 + tau * tau));
        double c = 1.0 / sqrt(1.0 + t * t);
        double s = t * c;
        // A <- A*J (column update)
        #pragma unroll
        for (int kk = 0; kk < 6; ++kk) {
            double akp = A[kk][P], akq = A[kk][Q];
            A[kk][P] = c * akp - s * akq;
            A[kk][Q] = s * akp + c * akq;
        }
        // A <- J^T*A (row update)
        #pragma unroll
        for (int kk = 0; kk < 6; ++kk) {
            double apk = A[P][kk], aqk = A[Q][kk];
            A[P][kk] = c * apk - s * aqk;
            A[Q][kk] = s * apk + c * aqk;
        }
        // V <- V*J
        #pragma unroll
        for (int kk = 0; kk < 6; ++kk) {
            double vkp = V[kk][P], vkq = V[kk][Q];
            V[kk][P] = c * vkp - s * vkq;
            V[kk][Q] = s * vkp + c * vkq;
        }
    }
}

__device__ __forceinline__ void jacobi6(double (&A)[6][6], double (&V)[6][6], int sweeps) {
    #pragma unroll
    for (int i = 0; i < 6; ++i)
        #pragma unroll
        for (int j = 0; j < 6; ++j)
            V[i][j] = (i == j) ? 1.0 : 0.0;
    for (int sw = 0; sw < sweeps; ++sw) {
        jrot<0,1>(A,V); jrot<0,2>(A,V); jrot<0,3>(A,V); jrot<0,4>(A,V); jrot<0,5>(A,V);
        jrot<1,2>(A,V); jrot<1,3>(A,V); jrot<1,4>(A,V); jrot<1,5>(A,V);
        jrot<2,3>(A,V); jrot<2,4>(A,V); jrot<2,5>(A,V);
        jrot<3,4>(A,V); jrot<3,5>(A,V);
        jrot<4,5>(A,V);
    }
}

__global__ __launch_bounds__(64, 1)
void curv_kernel(const float* __restrict__ depth, float* __restrict__ out) {
    int k = blockIdx.x * 64 + threadIdx.x;
    if (k >= 16384) return;
    int pi = k >> 7, pj = k & 127;
    int baseR = pi * 8 - 1;   // image row of local r=0 (may be -1 -> pad)
    int baseC = pj * 8 - 1;   // image col of local c=0 (may be -1 -> pad)

    double d36 = (double)depth[(pi * 8 + 3) * IMGW + (pj * 8 + 3)];
    double x36 = (double)(pj * 8 + 3);
    double y36 = (double)(pi * 8 + 3);

    // ---- accumulate 9x9 Gram (upper triangle, 45 entries) in f64 ----
    double S[45];
    #pragma unroll
    for (int i = 0; i < 45; ++i) S[i] = 0.0;

    for (int r = 0; r < 8; ++r) {
        int ir = baseR + r;
        bool rowpad = (ir < 0);
        #pragma unroll
        for (int c = 0; c < 8; ++c) {
            int ic = baseC + c;
            bool pad = rowpad || (ic < 0);
            float dv = 0.0f;
            if (!pad) dv = depth[ir * IMGW + ic];
            double p1 = (pad ? 0.0 : (double)ic) - x36;
            double p2 = (pad ? 0.0 : (double)ir) - y36;
            double p3 = (double)dv - d36;  // dv==0 on pad, matching reference
            double d9[9];
            d9[0] = p1 * p1; d9[1] = p2 * p2; d9[2] = p3 * p3;
            d9[3] = 2.0 * p1 * p2; d9[4] = 2.0 * p1 * p3; d9[5] = 2.0 * p2 * p3;
            d9[6] = 2.0 * p1; d9[7] = 2.0 * p2; d9[8] = 2.0 * p3;
            #pragma unroll
            for (int m = 0; m < 9; ++m)
                #pragma unroll
                for (int n = m; n < 9; ++n)
                    S[SIDX(m,n)] = fma(d9[m], d9[n], S[SIDX(m,n)]);
        }
    }

    // ---- G = S[6:9,6:9]; analytic inverse ----
    double g00 = S[SIDX(6,6)], g01 = S[SIDX(6,7)], g02 = S[SIDX(6,8)];
    double g11 = S[SIDX(7,7)], g12 = S[SIDX(7,8)], g22 = S[SIDX(8,8)];
    double c00 = g11 * g22 - g12 * g12;
    double c01 = g02 * g12 - g01 * g22;
    double c02 = g01 * g12 - g02 * g11;
    double det = g00 * c00 + g01 * c01 + g02 * c02;
    double invdet = 1.0 / det;
    double gi00 = c00 * invdet, gi01 = c01 * invdet, gi02 = c02 * invdet;
    double gi11 = (g00 * g22 - g02 * g02) * invdet;
    double gi12 = (g01 * g02 - g00 * g12) * invdet;
    double gi22 = (g00 * g11 - g01 * g01) * invdet;

    // ---- A = S11 - S12 G^{-1} S12^T (6x6 symmetric) ----
    double B0[6], B1[6], B2[6], T0[6], T1[6], T2[6];
    #pragma unroll
    for (int m = 0; m < 6; ++m) {
        B0[m] = S[SIDX(m,6)]; B1[m] = S[SIDX(m,7)]; B2[m] = S[SIDX(m,8)];
    }
    #pragma unroll
    for (int m = 0; m < 6; ++m) {
        T0[m] = gi00 * B0[m] + gi01 * B1[m] + gi02 * B2[m];
        T1[m] = gi01 * B0[m] + gi11 * B1[m] + gi12 * B2[m];
        T2[m] = gi02 * B0[m] + gi12 * B1[m] + gi22 * B2[m];
    }
    double A6[6][6];
    #pragma unroll
    for (int m = 0; m < 6; ++m)
        #pragma unroll
        for (int n = m; n < 6; ++n) {
            double val = S[SIDX(m,n)] - (B0[m] * T0[n] + B1[m] * T1[n] + B2[m] * T2[n]);
            A6[m][n] = val; A6[n][m] = val;
        }

    // ---- Jacobi #1: A = Q Lam Q^T ----
    double V1[6][6];
    jacobi6(A6, V1, 8);
    double lam[6];
    #pragma unroll
    for (int i = 0; i < 6; ++i) lam[i] = A6[i][i];
    double lmax = lam[0];
    #pragma unroll
    for (int i = 1; i < 6; ++i) lmax = fmax(lmax, lam[i]);
    double lfloor = lmax * 1e-14 + 1e-280;
    double s_[6], is_[6];
    #pragma unroll
    for (int i = 0; i < 6; ++i) {
        double l = fmax(lam[i], lfloor);
        s_[i] = sqrt(l);
        is_[i] = 1.0 / s_[i];
    }

    // ---- Ms = diag(s) Q^T Cinv Q diag(s);  Cinv = blockdiag((J-I)/2, -I/4) ----
    double M2[6][6];
    #pragma unroll
    for (int j2 = 0; j2 < 6; ++j2) {
        double yc[6];
        yc[0] = 0.5 * (V1[1][j2] + V1[2][j2]);
        yc[1] = 0.5 * (V1[0][j2] + V1[2][j2]);
        yc[2] = 0.5 * (V1[0][j2] + V1[1][j2]);
        yc[3] = -0.25 * V1[3][j2];
        yc[4] = -0.25 * V1[4][j2];
        yc[5] = -0.25 * V1[5][j2];
        #pragma unroll
        for (int i2 = 0; i2 < 6; ++i2) {
            if (i2 <= j2) {
                double w = 0.0;
                #pragma unroll
                for (int kk = 0; kk < 6; ++kk) w = fma(V1[kk][i2], yc[kk], w);
                double val = s_[i2] * s_[j2] * w;
                M2[i2][j2] = val; M2[j2][i2] = val;
            }
        }
    }

    // Fold inverse scaling into V1: U[m][i] = V1[m][i] / s_i
    #pragma unroll
    for (int m = 0; m < 6; ++m)
        #pragma unroll
        for (int i = 0; i < 6; ++i)
            V1[m][i] *= is_[i];

    // ---- Jacobi #2 on Ms; pick eigenvector of LARGEST eigenvalue ----
    double V2[6][6];
    jacobi6(M2, V2, 8);
    double l2max = M2[0][0];
    int imax = 0;
    #pragma unroll
    for (int i = 1; i < 6; ++i) {
        if (M2[i][i] > l2max) { l2max = M2[i][i]; imax = i; }
    }
    double y6[6];
    #pragma unroll
    for (int i2 = 0; i2 < 6; ++i2) {
        double acc = 0.0;
        #pragma unroll
        for (int jj = 0; jj < 6; ++jj) acc += (jj == imax) ? V2[i2][jj] : 0.0;
        y6[i2] = acc;
    }
    // v = U * y  (only first 6 quadric coefficients needed)
    double vq[6];
    #pragma unroll
    for (int m = 0; m < 6; ++m) {
        double acc = 0.0;
        #pragma unroll
        for (int i2 = 0; i2 < 6; ++i2) acc = fma(V1[m][i2], y6[i2], acc);
        vq[m] = acc;
    }

    // ---- 3x3 symmetric eigenvalues of K = [[v0,v3,v4],[v3,v1,v5],[v4,v5,v2]] ----
    double a = vq[0], b = vq[1], cc = vq[2], d = vq[3], e = vq[4], f = vq[5];
    double ev0, ev1, ev2;
    double off = d * d + e * e + f * f;
    if (off == 0.0) {
        ev0 = a; ev1 = b; ev2 = cc;
    } else {
        double q = (a + b + cc) / 3.0;
        double p2 = (a - q) * (a - q) + (b - q) * (b - q) + (cc - q) * (cc - q) + 2.0 * off;
        double p = sqrt(p2 / 6.0);
        double ip = 1.0 / p;
        double b00 = (a - q) * ip, b11 = (b - q) * ip, b22 = (cc - q) * ip;
        double b01 = d * ip, b02 = e * ip, b12 = f * ip;
        double detB = b00 * (b11 * b22 - b12 * b12)
                    - b01 * (b01 * b22 - b12 * b02)
                    + b02 * (b01 * b12 - b11 * b02);
        double rr = 0.5 * detB;
        rr = fmin(1.0, fmax(-1.0, rr));
        double phi = acos(rr) / 3.0;
        ev0 = q + 2.0 * p * cos(phi);
        ev2 = q + 2.0 * p * cos(phi + 2.0 * M_PI / 3.0);
        ev1 = 3.0 * q - ev0 - ev2;
    }
    double A0 = fabs(ev0), A1 = fabs(ev1), A2 = fabs(ev2);
    double mx = fmax(A0, fmax(A1, A2));
    double mn = fmin(A0, fmin(A1, A2));
    double simi = sqrt(fmax(mn, 1e-9) / fmax(mx, 1e-9));
    out[k] = (float)simi;
}

extern "C" void kernel_launch(void* const* d_in, const int* in_sizes, int n_in,
                              void* d_out, int out_size, void* d_ws, size_t ws_size,
                              hipStream_t stream) {
    const float* depth = (const float*)d_in[0];
    float* out = (float*)d_out;
    curv_kernel<<<dim3(256), dim3(64), 0, stream>>>(depth, out);
}

// Round 2
// 54.003 us; speedup vs baseline: 2.0190x; 2.0190x over previous
//
#include <hip/hip_runtime.h>
#include <math.h>

#ifndef M_PI
#define M_PI 3.14159265358979323846
#endif

#define IMGW 1024
#define SIDX(m,n) ((m)*9 - ((m)*((m)-1))/2 + ((n)-(m)))

// One f32 Jacobi rotation in the (P,Q) plane on a 6x6 symmetric matrix,
// accumulating eigenvectors into V. Division-free: hardware rcp/rsq/sqrt.
template<int P, int Q>
__device__ __forceinline__ void jrotf(float (&A)[6][6], float (&V)[6][6]) {
    float apq = A[P][Q];
    if (fabsf(apq) > 1e-30f) {
        float app = A[P][P], aqq = A[Q][Q];
        float tau = (aqq - app) * __builtin_amdgcn_rcpf(2.0f * apq);
        float t = copysignf(1.0f, tau) *
                  __builtin_amdgcn_rcpf(fabsf(tau) + sqrtf(fmaf(tau, tau, 1.0f)));
        float c = __builtin_amdgcn_rsqf(fmaf(t, t, 1.0f));
        float s = t * c;
        #pragma unroll
        for (int kk = 0; kk < 6; ++kk) {
            float akp = A[kk][P], akq = A[kk][Q];
            A[kk][P] = fmaf(c, akp, -s * akq);
            A[kk][Q] = fmaf(s, akp, c * akq);
        }
        #pragma unroll
        for (int kk = 0; kk < 6; ++kk) {
            float apk = A[P][kk], aqk = A[Q][kk];
            A[P][kk] = fmaf(c, apk, -s * aqk);
            A[Q][kk] = fmaf(s, apk, c * aqk);
        }
        #pragma unroll
        for (int kk = 0; kk < 6; ++kk) {
            float vkp = V[kk][P], vkq = V[kk][Q];
            V[kk][P] = fmaf(c, vkp, -s * vkq);
            V[kk][Q] = fmaf(s, vkp, c * vkq);
        }
    }
}

__device__ __forceinline__ void jacobi6f(float (&A)[6][6], float (&V)[6][6], int sweeps) {
    #pragma unroll
    for (int i = 0; i < 6; ++i)
        #pragma unroll
        for (int j = 0; j < 6; ++j)
            V[i][j] = (i == j) ? 1.0f : 0.0f;
    for (int sw = 0; sw < sweeps; ++sw) {
        jrotf<0,1>(A,V); jrotf<0,2>(A,V); jrotf<0,3>(A,V); jrotf<0,4>(A,V); jrotf<0,5>(A,V);
        jrotf<1,2>(A,V); jrotf<1,3>(A,V); jrotf<1,4>(A,V); jrotf<1,5>(A,V);
        jrotf<2,3>(A,V); jrotf<2,4>(A,V); jrotf<2,5>(A,V);
        jrotf<3,4>(A,V); jrotf<3,5>(A,V);
        jrotf<4,5>(A,V);
    }
}

__global__ __launch_bounds__(64, 1)
void curv_kernel(const float* __restrict__ depth, float* __restrict__ out) {
    int k = blockIdx.x * 64 + threadIdx.x;
    if (k >= 16384) return;
    int pi = k >> 7, pj = k & 127;
    int baseR = pi * 8 - 1;
    int baseC = pj * 8 - 1;

    double d36 = (double)depth[(pi * 8 + 3) * IMGW + (pj * 8 + 3)];
    double x36 = (double)(pj * 8 + 3);
    double y36 = (double)(pi * 8 + 3);

    // ---- accumulate 9x9 Gram (upper triangle, 45 entries) in f64 ----
    double S[45];
    #pragma unroll
    for (int i = 0; i < 45; ++i) S[i] = 0.0;

    for (int r = 0; r < 8; ++r) {
        int ir = baseR + r;
        bool rowpad = (ir < 0);
        #pragma unroll
        for (int c = 0; c < 8; ++c) {
            int ic = baseC + c;
            bool pad = rowpad || (ic < 0);
            float dv = 0.0f;
            if (!pad) dv = depth[ir * IMGW + ic];
            double p1 = (pad ? 0.0 : (double)ic) - x36;
            double p2 = (pad ? 0.0 : (double)ir) - y36;
            double p3 = (double)dv - d36;
            double d9[9];
            d9[0] = p1 * p1; d9[1] = p2 * p2; d9[2] = p3 * p3;
            d9[3] = 2.0 * p1 * p2; d9[4] = 2.0 * p1 * p3; d9[5] = 2.0 * p2 * p3;
            d9[6] = 2.0 * p1; d9[7] = 2.0 * p2; d9[8] = 2.0 * p3;
            #pragma unroll
            for (int m = 0; m < 9; ++m)
                #pragma unroll
                for (int n = m; n < 9; ++n)
                    S[SIDX(m,n)] = fma(d9[m], d9[n], S[SIDX(m,n)]);
        }
    }

    // ---- G = S[6:9,6:9]; analytic inverse (f64) ----
    double g00 = S[SIDX(6,6)], g01 = S[SIDX(6,7)], g02 = S[SIDX(6,8)];
    double g11 = S[SIDX(7,7)], g12 = S[SIDX(7,8)], g22 = S[SIDX(8,8)];
    double c00 = g11 * g22 - g12 * g12;
    double c01 = g02 * g12 - g01 * g22;
    double c02 = g01 * g12 - g02 * g11;
    double det = g00 * c00 + g01 * c01 + g02 * c02;
    double invdet = 1.0 / det;
    double gi00 = c00 * invdet, gi01 = c01 * invdet, gi02 = c02 * invdet;
    double gi11 = (g00 * g22 - g02 * g02) * invdet;
    double gi12 = (g01 * g02 - g00 * g12) * invdet;
    double gi22 = (g00 * g11 - g01 * g01) * invdet;

    // ---- A = S11 - S12 G^{-1} S12^T (6x6 symmetric, f64) -> cast f32 ----
    double B0[6], B1[6], B2[6], T0[6], T1[6], T2[6];
    #pragma unroll
    for (int m = 0; m < 6; ++m) {
        B0[m] = S[SIDX(m,6)]; B1[m] = S[SIDX(m,7)]; B2[m] = S[SIDX(m,8)];
    }
    #pragma unroll
    for (int m = 0; m < 6; ++m) {
        T0[m] = gi00 * B0[m] + gi01 * B1[m] + gi02 * B2[m];
        T1[m] = gi01 * B0[m] + gi11 * B1[m] + gi12 * B2[m];
        T2[m] = gi02 * B0[m] + gi12 * B1[m] + gi22 * B2[m];
    }
    float A6[6][6];
    #pragma unroll
    for (int m = 0; m < 6; ++m)
        #pragma unroll
        for (int n = m; n < 6; ++n) {
            double val = S[SIDX(m,n)] - (B0[m] * T0[n] + B1[m] * T1[n] + B2[m] * T2[n]);
            A6[m][n] = (float)val; A6[n][m] = (float)val;
        }

    // ---- Jacobi #1 (f32): A = Q Lam Q^T ----
    float V1[6][6];
    jacobi6f(A6, V1, 6);
    float lam[6];
    #pragma unroll
    for (int i = 0; i < 6; ++i) lam[i] = A6[i][i];
    float lmax = lam[0];
    #pragma unroll
    for (int i = 1; i < 6; ++i) lmax = fmaxf(lmax, lam[i]);
    float lfloor = lmax * 1e-10f + 1e-30f;
    float s_[6], is_[6];
    #pragma unroll
    for (int i = 0; i < 6; ++i) {
        float l = fmaxf(lam[i], lfloor);
        s_[i] = sqrtf(l);
        is_[i] = __builtin_amdgcn_rcpf(s_[i]);
    }

    // ---- Ms = diag(s) Q^T Cinv Q diag(s);  Cinv = blockdiag((J-I)/2, -I/4) ----
    float M2[6][6];
    #pragma unroll
    for (int j2 = 0; j2 < 6; ++j2) {
        float yc[6];
        yc[0] = 0.5f * (V1[1][j2] + V1[2][j2]);
        yc[1] = 0.5f * (V1[0][j2] + V1[2][j2]);
        yc[2] = 0.5f * (V1[0][j2] + V1[1][j2]);
        yc[3] = -0.25f * V1[3][j2];
        yc[4] = -0.25f * V1[4][j2];
        yc[5] = -0.25f * V1[5][j2];
        #pragma unroll
        for (int i2 = 0; i2 < 6; ++i2) {
            if (i2 <= j2) {
                float w = 0.0f;
                #pragma unroll
                for (int kk = 0; kk < 6; ++kk) w = fmaf(V1[kk][i2], yc[kk], w);
                float val = s_[i2] * s_[j2] * w;
                M2[i2][j2] = val; M2[j2][i2] = val;
            }
        }
    }

    // Fold inverse scaling into V1: U[m][i] = V1[m][i] / s_i
    #pragma unroll
    for (int m = 0; m < 6; ++m)
        #pragma unroll
        for (int i = 0; i < 6; ++i)
            V1[m][i] *= is_[i];

    // ---- Jacobi #2 (f32) on Ms; eigenvector of LARGEST eigenvalue ----
    float V2[6][6];
    jacobi6f(M2, V2, 6);
    float l2max = M2[0][0];
    int imax = 0;
    #pragma unroll
    for (int i = 1; i < 6; ++i) {
        if (M2[i][i] > l2max) { l2max = M2[i][i]; imax = i; }
    }
    float y6[6];
    #pragma unroll
    for (int i2 = 0; i2 < 6; ++i2) {
        float acc = 0.0f;
        #pragma unroll
        for (int jj = 0; jj < 6; ++jj) acc += (jj == imax) ? V2[i2][jj] : 0.0f;
        y6[i2] = acc;
    }
    // v = U * y  (first 6 quadric coefficients)
    double vq[6];
    #pragma unroll
    for (int m = 0; m < 6; ++m) {
        float acc = 0.0f;
        #pragma unroll
        for (int i2 = 0; i2 < 6; ++i2) acc = fmaf(V1[m][i2], y6[i2], acc);
        vq[m] = (double)acc;
    }

    // ---- 3x3 symmetric eigenvalues (closed form, f64) ----
    double a = vq[0], b = vq[1], cc = vq[2], d = vq[3], e = vq[4], f = vq[5];
    double ev0, ev1, ev2;
    double off = d * d + e * e + f * f;
    if (off == 0.0) {
        ev0 = a; ev1 = b; ev2 = cc;
    } else {
        double q = (a + b + cc) / 3.0;
        double p2 = (a - q) * (a - q) + (b - q) * (b - q) + (cc - q) * (cc - q) + 2.0 * off;
        double p = sqrt(p2 / 6.0);
        double ip = 1.0 / p;
        double b00 = (a - q) * ip, b11 = (b - q) * ip, b22 = (cc - q) * ip;
        double b01 = d * ip, b02 = e * ip, b12 = f * ip;
        double detB = b00 * (b11 * b22 - b12 * b12)
                    - b01 * (b01 * b22 - b12 * b02)
                    + b02 * (b01 * b12 - b11 * b02);
        double rr = 0.5 * detB;
        rr = fmin(1.0, fmax(-1.0, rr));
        double phi = acos(rr) / 3.0;
        ev0 = q + 2.0 * p * cos(phi);
        ev2 = q + 2.0 * p * cos(phi + 2.0 * M_PI / 3.0);
        ev1 = 3.0 * q - ev0 - ev2;
    }
    double A0 = fabs(ev0), A1 = fabs(ev1), A2 = fabs(ev2);
    double mx = fmax(A0, fmax(A1, A2));
    double mn = fmin(A0, fmin(A1, A2));
    double simi = sqrt(fmax(mn, 1e-9) / fmax(mx, 1e-9));
    out[k] = (float)simi;
}

extern "C" void kernel_launch(void* const* d_in, const int* in_sizes, int n_in,
                              void* d_out, int out_size, void* d_ws, size_t ws_size,
                              hipStream_t stream) {
    const float* depth = (const float*)d_in[0];
    float* out = (float*)d_out;
    curv_kernel<<<dim3(256), dim3(64), 0, stream>>>(depth, out);
}

// Round 3
// 41.057 us; speedup vs baseline: 2.6556x; 1.3153x over previous
//
#include <hip/hip_runtime.h>
#include <math.h>

#ifndef M_PI
#define M_PI 3.14159265358979323846
#endif

#define IMGW 1024
#define SIDX(m,n) ((m)*9 - ((m)*((m)-1))/2 + ((n)-(m)))

// Branchless f32 Jacobi rotation in the (P,Q) plane; accumulates eigvecs in V.
template<int P, int Q>
__device__ __forceinline__ void jrotf(float (&A)[6][6], float (&V)[6][6]) {
    float apq = A[P][Q];
    float app = A[P][P], aqq = A[Q][Q];
    float tau = (aqq - app) * __builtin_amdgcn_rcpf(2.0f * apq);
    float t = copysignf(__builtin_amdgcn_rcpf(fabsf(tau) + sqrtf(fmaf(tau, tau, 1.0f))), tau);
    bool ok = fabsf(apq) > 1e-20f;
    t = ok ? t : 0.0f;
    float c = __builtin_amdgcn_rsqf(fmaf(t, t, 1.0f));
    float s = t * c;
    #pragma unroll
    for (int kk = 0; kk < 6; ++kk) {
        float akp = A[kk][P], akq = A[kk][Q];
        A[kk][P] = fmaf(c, akp, -s * akq);
        A[kk][Q] = fmaf(s, akp, c * akq);
    }
    #pragma unroll
    for (int kk = 0; kk < 6; ++kk) {
        float apk = A[P][kk], aqk = A[Q][kk];
        A[P][kk] = fmaf(c, apk, -s * aqk);
        A[Q][kk] = fmaf(s, apk, c * aqk);
    }
    #pragma unroll
    for (int kk = 0; kk < 6; ++kk) {
        float vkp = V[kk][P], vkq = V[kk][Q];
        V[kk][P] = fmaf(c, vkp, -s * vkq);
        V[kk][Q] = fmaf(s, vkp, c * vkq);
    }
}

__device__ __forceinline__ void jacobi6f(float (&A)[6][6], float (&V)[6][6], int sweeps) {
    #pragma unroll
    for (int i = 0; i < 6; ++i)
        #pragma unroll
        for (int j = 0; j < 6; ++j)
            V[i][j] = (i == j) ? 1.0f : 0.0f;
    for (int sw = 0; sw < sweeps; ++sw) {
        jrotf<0,1>(A,V); jrotf<0,2>(A,V); jrotf<0,3>(A,V); jrotf<0,4>(A,V); jrotf<0,5>(A,V);
        jrotf<1,2>(A,V); jrotf<1,3>(A,V); jrotf<1,4>(A,V); jrotf<1,5>(A,V);
        jrotf<2,3>(A,V); jrotf<2,4>(A,V); jrotf<2,5>(A,V);
        jrotf<3,4>(A,V); jrotf<3,5>(A,V);
        jrotf<4,5>(A,V);
    }
}

// Gram + G^{-1} + Schur complement in precision T. PAD=true handles top/left
// zero-padding (boundary patches); PAD=false assumes fully interior patch.
template<typename T, bool PAD>
__device__ __forceinline__ void buildA(const float* __restrict__ depth,
                                       int pi, int pj, float (&A6)[6][6]) {
    int baseR = pi * 8 - 1;
    int baseC = pj * 8 - 1;
    T d36 = (T)depth[(pi * 8 + 3) * IMGW + (pj * 8 + 3)];
    T x36 = (T)(pj * 8 + 3);
    T y36 = (T)(pi * 8 + 3);

    T S[45];
    #pragma unroll
    for (int i = 0; i < 45; ++i) S[i] = (T)0;

    for (int r = 0; r < 8; ++r) {
        int ir = baseR + r;
        bool rowpad = PAD && (ir < 0);
        #pragma unroll
        for (int c = 0; c < 8; ++c) {
            int ic = baseC + c;
            bool pad = PAD && (rowpad || ic < 0);
            float dv = 0.0f;
            if (!pad) dv = depth[ir * IMGW + ic];
            T p1 = (pad ? (T)0 : (T)ic) - x36;
            T p2 = (pad ? (T)0 : (T)ir) - y36;
            T p3 = (T)dv - d36;
            T d9[9];
            d9[0] = p1 * p1; d9[1] = p2 * p2; d9[2] = p3 * p3;
            d9[3] = (T)2 * p1 * p2; d9[4] = (T)2 * p1 * p3; d9[5] = (T)2 * p2 * p3;
            d9[6] = (T)2 * p1; d9[7] = (T)2 * p2; d9[8] = (T)2 * p3;
            #pragma unroll
            for (int m = 0; m < 9; ++m)
                #pragma unroll
                for (int n = m; n < 9; ++n)
                    S[SIDX(m,n)] += d9[m] * d9[n];
        }
    }

    // G = S[6:9,6:9] analytic inverse
    T g00 = S[SIDX(6,6)], g01 = S[SIDX(6,7)], g02 = S[SIDX(6,8)];
    T g11 = S[SIDX(7,7)], g12 = S[SIDX(7,8)], g22 = S[SIDX(8,8)];
    T c00 = g11 * g22 - g12 * g12;
    T c01 = g02 * g12 - g01 * g22;
    T c02 = g01 * g12 - g02 * g11;
    T det = g00 * c00 + g01 * c01 + g02 * c02;
    T invdet = (T)1 / det;
    T gi00 = c00 * invdet, gi01 = c01 * invdet, gi02 = c02 * invdet;
    T gi11 = (g00 * g22 - g02 * g02) * invdet;
    T gi12 = (g01 * g02 - g00 * g12) * invdet;
    T gi22 = (g00 * g11 - g01 * g01) * invdet;

    T B0[6], B1[6], B2[6], T0[6], T1[6], T2[6];
    #pragma unroll
    for (int m = 0; m < 6; ++m) {
        B0[m] = S[SIDX(m,6)]; B1[m] = S[SIDX(m,7)]; B2[m] = S[SIDX(m,8)];
    }
    #pragma unroll
    for (int m = 0; m < 6; ++m) {
        T0[m] = gi00 * B0[m] + gi01 * B1[m] + gi02 * B2[m];
        T1[m] = gi01 * B0[m] + gi11 * B1[m] + gi12 * B2[m];
        T2[m] = gi02 * B0[m] + gi12 * B1[m] + gi22 * B2[m];
    }
    #pragma unroll
    for (int m = 0; m < 6; ++m)
        #pragma unroll
        for (int n = m; n < 6; ++n) {
            T val = S[SIDX(m,n)] - (B0[m] * T0[n] + B1[m] * T1[n] + B2[m] * T2[n]);
            A6[m][n] = (float)val; A6[n][m] = (float)val;
        }
}

__global__ __launch_bounds__(64, 1)
void curv_kernel(const float* __restrict__ depth, float* __restrict__ out) {
    unsigned k = blockIdx.x * 64u + threadIdx.x;
    if (k >= 16384u) return;

    // Remap so boundary patches (pi==0 || pj==0, f64 path) occupy tail waves.
    int pi, pj;
    bool boundary;
    if (k < 16129u) {           // 127*127 interior patches
        pi = 1 + (int)(k / 127u);
        pj = 1 + (int)(k % 127u);
        boundary = false;
    } else {
        unsigned b = k - 16129u;  // 0..254
        if (b < 128u) { pi = 0; pj = (int)b; }
        else          { pi = (int)(b - 127u); pj = 0; }
        boundary = true;
    }

    float A6[6][6];
    if (boundary) buildA<double, true >(depth, pi, pj, A6);
    else          buildA<float,  false>(depth, pi, pj, A6);

    // ---- Cholesky A + ridge = L L^T ----
    float tr = A6[0][0] + A6[1][1] + A6[2][2] + A6[3][3] + A6[4][4] + A6[5][5];
    float ridge = 1e-6f * tr + 1e-30f;
    float dfloor = 1e-12f * tr + 1e-30f;
    float L[6][6];
    #pragma unroll
    for (int i = 0; i < 6; ++i)
        #pragma unroll
        for (int j = 0; j < 6; ++j)
            L[i][j] = 0.0f;
    #pragma unroll
    for (int j = 0; j < 6; ++j) {
        float d = A6[j][j] + ridge;
        #pragma unroll
        for (int kk = 0; kk < 6; ++kk)
            if (kk < j) d = fmaf(-L[j][kk], L[j][kk], d);
        d = fmaxf(d, dfloor);
        float sd = sqrtf(d);
        float isd = __builtin_amdgcn_rcpf(sd);
        L[j][j] = sd;
        #pragma unroll
        for (int i = 0; i < 6; ++i) {
            if (i > j) {
                float v = A6[i][j];
                #pragma unroll
                for (int kk = 0; kk < 6; ++kk)
                    if (kk < j) v = fmaf(-L[i][kk], L[j][kk], v);
                L[i][j] = v * isd;
            }
        }
    }

    // ---- Ms = L^T Cinv L; Cinv = blockdiag((J-I)/2, -I/4) ----
    float N[6][6];
    #pragma unroll
    for (int j = 0; j < 6; ++j) {
        N[0][j] = 0.5f * (L[1][j] + L[2][j]);
        N[1][j] = 0.5f * (L[0][j] + L[2][j]);
        N[2][j] = 0.5f * (L[0][j] + L[1][j]);
        N[3][j] = -0.25f * L[3][j];
        N[4][j] = -0.25f * L[4][j];
        N[5][j] = -0.25f * L[5][j];
    }
    float Ms[6][6];
    #pragma unroll
    for (int i = 0; i < 6; ++i)
        #pragma unroll
        for (int j = 0; j < 6; ++j) {
            if (i <= j) {
                float acc = 0.0f;
                #pragma unroll
                for (int kk = 0; kk < 6; ++kk)
                    acc = fmaf(L[kk][i], N[kk][j], acc);
                Ms[i][j] = acc; Ms[j][i] = acc;
            }
        }

    // ---- Jacobi on Ms; eigenvector of LARGEST eigenvalue ----
    float W[6][6];
    jacobi6f(Ms, W, 5);
    float l2max = Ms[0][0];
    int imax = 0;
    #pragma unroll
    for (int i = 1; i < 6; ++i) {
        if (Ms[i][i] > l2max) { l2max = Ms[i][i]; imax = i; }
    }
    float y6[6];
    #pragma unroll
    for (int i = 0; i < 6; ++i) {
        float acc = 0.0f;
        #pragma unroll
        for (int jj = 0; jj < 6; ++jj) acc += (jj == imax) ? W[i][jj] : 0.0f;
        y6[i] = acc;
    }

    // ---- v = L^{-T} y (back-substitution) ----
    float v5 = y6[5] * __builtin_amdgcn_rcpf(L[5][5]);
    float v4 = (y6[4] - L[5][4]*v5) * __builtin_amdgcn_rcpf(L[4][4]);
    float v3 = (y6[3] - L[4][3]*v4 - L[5][3]*v5) * __builtin_amdgcn_rcpf(L[3][3]);
    float v2 = (y6[2] - L[3][2]*v3 - L[4][2]*v4 - L[5][2]*v5) * __builtin_amdgcn_rcpf(L[2][2]);
    float v1 = (y6[1] - L[2][1]*v2 - L[3][1]*v3 - L[4][1]*v4 - L[5][1]*v5) * __builtin_amdgcn_rcpf(L[1][1]);
    float v0 = (y6[0] - L[1][0]*v1 - L[2][0]*v2 - L[3][0]*v3 - L[4][0]*v4 - L[5][0]*v5) * __builtin_amdgcn_rcpf(L[0][0]);

    // ---- 3x3 symmetric eigenvalue ratio (closed form, f32) ----
    float a = v0, b = v1, cc = v2, d = v3, e = v4, f = v5;
    float ev0, ev1, ev2;
    float off = d * d + e * e + f * f;
    if (off == 0.0f) {
        ev0 = a; ev1 = b; ev2 = cc;
    } else {
        float q = (a + b + cc) * (1.0f / 3.0f);
        float p2 = (a-q)*(a-q) + (b-q)*(b-q) + (cc-q)*(cc-q) + 2.0f * off;
        float p = sqrtf(p2 * (1.0f / 6.0f));
        float ip = __builtin_amdgcn_rcpf(p);
        float b00 = (a - q) * ip, b11 = (b - q) * ip, b22 = (cc - q) * ip;
        float b01 = d * ip, b02 = e * ip, b12 = f * ip;
        float detB = b00 * (b11 * b22 - b12 * b12)
                   - b01 * (b01 * b22 - b12 * b02)
                   + b02 * (b01 * b12 - b11 * b02);
        float rr = 0.5f * detB;
        rr = fminf(1.0f, fmaxf(-1.0f, rr));
        float phi = acosf(rr) * (1.0f / 3.0f);
        ev0 = q + 2.0f * p * cosf(phi);
        ev2 = q + 2.0f * p * cosf(phi + (float)(2.0 * M_PI / 3.0));
        ev1 = 3.0f * q - ev0 - ev2;
    }
    float A0 = fabsf(ev0), A1 = fabsf(ev1), A2 = fabsf(ev2);
    float mx = fmaxf(A0, fmaxf(A1, A2));
    float mn = fminf(A0, fminf(A1, A2));
    float simi = sqrtf(fmaxf(mn, 1e-9f) / fmaxf(mx, 1e-9f));

    out[pi * 128 + pj] = simi;
}

extern "C" void kernel_launch(void* const* d_in, const int* in_sizes, int n_in,
                              void* d_out, int out_size, void* d_ws, size_t ws_size,
                              hipStream_t stream) {
    const float* depth = (const float*)d_in[0];
    float* out = (float*)d_out;
    curv_kernel<<<dim3(256), dim3(64), 0, stream>>>(depth, out);
}

// Round 4
// 32.997 us; speedup vs baseline: 3.3042x; 1.2443x over previous
//
#include <hip/hip_runtime.h>
#include <math.h>

#ifndef M_PI
#define M_PI 3.14159265358979323846
#endif

#define IMGW 1024
#define SIDX(m,n) ((m)*9 - ((m)*((m)-1))/2 + ((n)-(m)))

// ---------------- Jacobi: parallel-ordered (3 disjoint rotations/round) ----
template<int P, int Q>
__device__ __forceinline__ void jangle(const float (&A)[6][6], float& c, float& s) {
    float apq = A[P][Q];
    float tau = (A[Q][Q] - A[P][P]) * __builtin_amdgcn_rcpf(2.0f * apq);
    float t = copysignf(__builtin_amdgcn_rcpf(fabsf(tau) + sqrtf(fmaf(tau, tau, 1.0f))), tau);
    t = (fabsf(apq) > 1e-20f) ? t : 0.0f;
    c = __builtin_amdgcn_rsqf(fmaf(t, t, 1.0f));
    s = t * c;
}

template<int P, int Q>
__device__ __forceinline__ void japply(float (&A)[6][6], float (&V)[6][6], float c, float s) {
    #pragma unroll
    for (int kk = 0; kk < 6; ++kk) {
        float akp = A[kk][P], akq = A[kk][Q];
        A[kk][P] = fmaf(c, akp, -s * akq);
        A[kk][Q] = fmaf(s, akp, c * akq);
    }
    #pragma unroll
    for (int kk = 0; kk < 6; ++kk) {
        float apk = A[P][kk], aqk = A[Q][kk];
        A[P][kk] = fmaf(c, apk, -s * aqk);
        A[Q][kk] = fmaf(s, apk, c * aqk);
    }
    #pragma unroll
    for (int kk = 0; kk < 6; ++kk) {
        float vkp = V[kk][P], vkq = V[kk][Q];
        V[kk][P] = fmaf(c, vkp, -s * vkq);
        V[kk][Q] = fmaf(s, vkp, c * vkq);
    }
}

template<int P0,int Q0,int P1,int Q1,int P2,int Q2>
__device__ __forceinline__ void jround3(float (&A)[6][6], float (&V)[6][6]) {
    float c0,s0,c1,s1,c2,s2;
    jangle<P0,Q0>(A, c0, s0);   // disjoint pivots: angles from same A = exact
    jangle<P1,Q1>(A, c1, s1);
    jangle<P2,Q2>(A, c2, s2);
    japply<P0,Q0>(A, V, c0, s0);
    japply<P1,Q1>(A, V, c1, s1);
    japply<P2,Q2>(A, V, c2, s2);
}

__device__ __forceinline__ void jacobi6f(float (&A)[6][6], float (&V)[6][6], int sweeps) {
    #pragma unroll
    for (int i = 0; i < 6; ++i)
        #pragma unroll
        for (int j = 0; j < 6; ++j)
            V[i][j] = (i == j) ? 1.0f : 0.0f;
    for (int sw = 0; sw < sweeps; ++sw) {
        jround3<0,5, 1,4, 2,3>(A, V);
        jround3<0,4, 3,5, 1,2>(A, V);
        jround3<0,3, 2,4, 1,5>(A, V);
        jround3<0,2, 1,3, 4,5>(A, V);
        jround3<0,1, 2,5, 3,4>(A, V);
    }
}

// ---------------- Schur complement S -> A6 (precision T) -------------------
template<typename T>
__device__ __forceinline__ void schur6(const T (&S)[45], float (&A6)[6][6]) {
    T g00 = S[SIDX(6,6)], g01 = S[SIDX(6,7)], g02 = S[SIDX(6,8)];
    T g11 = S[SIDX(7,7)], g12 = S[SIDX(7,8)], g22 = S[SIDX(8,8)];
    T c00 = g11 * g22 - g12 * g12;
    T c01 = g02 * g12 - g01 * g22;
    T c02 = g01 * g12 - g02 * g11;
    T det = g00 * c00 + g01 * c01 + g02 * c02;
    T invdet = (T)1 / det;
    T gi00 = c00 * invdet, gi01 = c01 * invdet, gi02 = c02 * invdet;
    T gi11 = (g00 * g22 - g02 * g02) * invdet;
    T gi12 = (g01 * g02 - g00 * g12) * invdet;
    T gi22 = (g00 * g11 - g01 * g01) * invdet;

    T B0[6], B1[6], B2[6], T0[6], T1[6], T2[6];
    #pragma unroll
    for (int m = 0; m < 6; ++m) {
        B0[m] = S[SIDX(m,6)]; B1[m] = S[SIDX(m,7)]; B2[m] = S[SIDX(m,8)];
    }
    #pragma unroll
    for (int m = 0; m < 6; ++m) {
        T0[m] = gi00 * B0[m] + gi01 * B1[m] + gi02 * B2[m];
        T1[m] = gi01 * B0[m] + gi11 * B1[m] + gi12 * B2[m];
        T2[m] = gi02 * B0[m] + gi12 * B1[m] + gi22 * B2[m];
    }
    #pragma unroll
    for (int m = 0; m < 6; ++m)
        #pragma unroll
        for (int n = m; n < 6; ++n) {
            T val = S[SIDX(m,n)] - (B0[m] * T0[n] + B1[m] * T1[n] + B2[m] * T2[n]);
            A6[m][n] = (float)val; A6[n][m] = (float)val;
        }
}

__global__ __launch_bounds__(64, 1)
void curv_kernel(const float* __restrict__ depth, float* __restrict__ out) {
    unsigned k = blockIdx.x * 64u + threadIdx.x;
    if (k >= 16384u) return;

    // Remap: boundary patches (pi==0 || pj==0) -> tail waves (wave-uniform path).
    int pi, pj;
    bool boundary;
    if (k < 16129u) {             // 127*127 interior patches
        pi = 1 + (int)(k / 127u);
        pj = 1 + (int)(k % 127u);
        boundary = false;
    } else {
        unsigned b = k - 16129u;  // 0..254
        if (b < 128u) { pi = 0; pj = (int)b; }
        else          { pi = (int)(b - 127u); pj = 0; }
        boundary = true;
    }

    float A6[6][6];

    if (!boundary) {
        // ---- fast interior Gram: constant xy-moments + 20 depth-weighted sums
        const float* pbase = depth + (pi * 8 - 1) * IMGW + (pj * 8 - 1);
        float d36 = pbase[4 * IMGW + 4];
        float W1_1=0,W1_u=0,W1_v=0,W1_uu=0,W1_uv=0,W1_vv=0,W1_u3=0,W1_uuv=0,W1_uvv=0,W1_v3=0;
        float W2_1=0,W2_u=0,W2_v=0,W2_uu=0,W2_uv=0,W2_vv=0;
        float W3_1=0,W3_u=0,W3_v=0,W4_1=0;
        #pragma unroll
        for (int r = 0; r < 8; ++r) {
            #pragma unroll
            for (int c = 0; c < 8; ++c) {
                float wv = pbase[r * IMGW + c] - d36;
                const float U = (float)(c - 4);
                const float Vv = (float)(r - 4);
                float w2 = wv * wv, w3 = w2 * wv, w4 = w2 * w2;
                W1_1 += wv;
                W1_u   = fmaf(U, wv, W1_u);
                W1_v   = fmaf(Vv, wv, W1_v);
                W1_uu  = fmaf(U * U, wv, W1_uu);
                W1_uv  = fmaf(U * Vv, wv, W1_uv);
                W1_vv  = fmaf(Vv * Vv, wv, W1_vv);
                W1_u3  = fmaf(U * U * U, wv, W1_u3);
                W1_uuv = fmaf(U * U * Vv, wv, W1_uuv);
                W1_uvv = fmaf(U * Vv * Vv, wv, W1_uvv);
                W1_v3  = fmaf(Vv * Vv * Vv, wv, W1_v3);
                W2_1 += w2;
                W2_u   = fmaf(U, w2, W2_u);
                W2_v   = fmaf(Vv, w2, W2_v);
                W2_uu  = fmaf(U * U, w2, W2_uu);
                W2_uv  = fmaf(U * Vv, w2, W2_uv);
                W2_vv  = fmaf(Vv * Vv, w2, W2_vv);
                W3_1 += w3;
                W3_u   = fmaf(U, w3, W3_u);
                W3_v   = fmaf(Vv, w3, W3_v);
                W4_1 += w4;
            }
        }
        float S[45];
        S[SIDX(0,0)] = 3616.0f;   S[SIDX(0,1)] = 1936.0f;  S[SIDX(0,2)] = W2_uu;
        S[SIDX(0,3)] = 512.0f;    S[SIDX(0,4)] = 2.0f*W1_u3; S[SIDX(0,5)] = 2.0f*W1_uuv;
        S[SIDX(0,6)] = -1024.0f;  S[SIDX(0,7)] = -352.0f;  S[SIDX(0,8)] = 2.0f*W1_uu;
        S[SIDX(1,1)] = 3616.0f;   S[SIDX(1,2)] = W2_vv;    S[SIDX(1,3)] = 512.0f;
        S[SIDX(1,4)] = 2.0f*W1_uvv; S[SIDX(1,5)] = 2.0f*W1_v3;
        S[SIDX(1,6)] = -352.0f;   S[SIDX(1,7)] = -1024.0f; S[SIDX(1,8)] = 2.0f*W1_vv;
        S[SIDX(2,2)] = W4_1;      S[SIDX(2,3)] = 2.0f*W2_uv;
        S[SIDX(2,4)] = 2.0f*W3_u; S[SIDX(2,5)] = 2.0f*W3_v;
        S[SIDX(2,6)] = 2.0f*W2_u; S[SIDX(2,7)] = 2.0f*W2_v; S[SIDX(2,8)] = 2.0f*W3_1;
        S[SIDX(3,3)] = 7744.0f;   S[SIDX(3,4)] = 4.0f*W1_uuv; S[SIDX(3,5)] = 4.0f*W1_uvv;
        S[SIDX(3,6)] = -704.0f;   S[SIDX(3,7)] = -704.0f;  S[SIDX(3,8)] = 4.0f*W1_uv;
        S[SIDX(4,4)] = 4.0f*W2_uu; S[SIDX(4,5)] = 4.0f*W2_uv;
        S[SIDX(4,6)] = 4.0f*W1_uu; S[SIDX(4,7)] = 4.0f*W1_uv; S[SIDX(4,8)] = 4.0f*W2_u;
        S[SIDX(5,5)] = 4.0f*W2_vv;
        S[SIDX(5,6)] = 4.0f*W1_uv; S[SIDX(5,7)] = 4.0f*W1_vv; S[SIDX(5,8)] = 4.0f*W2_v;
        S[SIDX(6,6)] = 1408.0f;   S[SIDX(6,7)] = 64.0f;    S[SIDX(6,8)] = 4.0f*W1_u;
        S[SIDX(7,7)] = 1408.0f;   S[SIDX(7,8)] = 4.0f*W1_v;
        S[SIDX(8,8)] = 4.0f*W2_1;
        schur6<float>(S, A6);
    } else {
        // ---- boundary: f32 interior-pixel Gram (pads zeroed) + exact f64 rank-1
        int baseR = pi * 8 - 1, baseC = pj * 8 - 1;
        float d36 = depth[(pi * 8 + 3) * IMGW + (pj * 8 + 3)];
        float S32[45];
        #pragma unroll
        for (int i = 0; i < 45; ++i) S32[i] = 0.0f;
        for (int r = 0; r < 8; ++r) {
            int ir = baseR + r;
            bool rowpad = (ir < 0);
            #pragma unroll
            for (int c = 0; c < 8; ++c) {
                int ic = baseC + c;
                bool pad = rowpad || (ic < 0);
                float dv = 0.0f;
                if (!pad) dv = depth[ir * IMGW + ic];
                float p1 = pad ? 0.0f : (float)(c - 4);
                float p2 = pad ? 0.0f : (float)(r - 4);
                float p3 = pad ? 0.0f : (dv - d36);
                float d9[9];
                d9[0] = p1 * p1; d9[1] = p2 * p2; d9[2] = p3 * p3;
                d9[3] = 2.0f * p1 * p2; d9[4] = 2.0f * p1 * p3; d9[5] = 2.0f * p2 * p3;
                d9[6] = 2.0f * p1; d9[7] = 2.0f * p2; d9[8] = 2.0f * p3;
                #pragma unroll
                for (int m = 0; m < 9; ++m)
                    #pragma unroll
                    for (int n = m; n < 9; ++n)
                        S32[SIDX(m,n)] = fmaf(d9[m], d9[n], S32[SIDX(m,n)]);
            }
        }
        // all pad pixels coincide at (0,0,0) absolute -> centered far point:
        double m = (double)((pi == 0 ? 8 : 0) + (pj == 0 ? 8 : 0) - ((pi == 0 && pj == 0) ? 1 : 0));
        double xf = -(double)(pj * 8 + 3);
        double yf = -(double)(pi * 8 + 3);
        double df = -(double)d36;
        double d9f[9];
        d9f[0] = xf * xf; d9f[1] = yf * yf; d9f[2] = df * df;
        d9f[3] = 2.0 * xf * yf; d9f[4] = 2.0 * xf * df; d9f[5] = 2.0 * yf * df;
        d9f[6] = 2.0 * xf; d9f[7] = 2.0 * yf; d9f[8] = 2.0 * df;
        double S64[45];
        #pragma unroll
        for (int mm = 0; mm < 9; ++mm)
            #pragma unroll
            for (int nn = mm; nn < 9; ++nn)
                S64[SIDX(mm,nn)] = (double)S32[SIDX(mm,nn)] + m * d9f[mm] * d9f[nn];
        schur6<double>(S64, A6);
    }

    // ---- Cholesky A + ridge = L L^T ----
    float tr = A6[0][0] + A6[1][1] + A6[2][2] + A6[3][3] + A6[4][4] + A6[5][5];
    float ridge = 1e-6f * tr + 1e-30f;
    float dfloor = 1e-12f * tr + 1e-30f;
    float L[6][6];
    #pragma unroll
    for (int i = 0; i < 6; ++i)
        #pragma unroll
        for (int j = 0; j < 6; ++j)
            L[i][j] = 0.0f;
    #pragma unroll
    for (int j = 0; j < 6; ++j) {
        float d = A6[j][j] + ridge;
        #pragma unroll
        for (int kk = 0; kk < 6; ++kk)
            if (kk < j) d = fmaf(-L[j][kk], L[j][kk], d);
        d = fmaxf(d, dfloor);
        float sd = sqrtf(d);
        float isd = __builtin_amdgcn_rcpf(sd);
        L[j][j] = sd;
        #pragma unroll
        for (int i = 0; i < 6; ++i) {
            if (i > j) {
                float v = A6[i][j];
                #pragma unroll
                for (int kk = 0; kk < 6; ++kk)
                    if (kk < j) v = fmaf(-L[i][kk], L[j][kk], v);
                L[i][j] = v * isd;
            }
        }
    }

    // ---- Ms = L^T Cinv L; Cinv = blockdiag((J-I)/2, -I/4) ----
    float N[6][6];
    #pragma unroll
    for (int j = 0; j < 6; ++j) {
        N[0][j] = 0.5f * (L[1][j] + L[2][j]);
        N[1][j] = 0.5f * (L[0][j] + L[2][j]);
        N[2][j] = 0.5f * (L[0][j] + L[1][j]);
        N[3][j] = -0.25f * L[3][j];
        N[4][j] = -0.25f * L[4][j];
        N[5][j] = -0.25f * L[5][j];
    }
    float Ms[6][6];
    #pragma unroll
    for (int i = 0; i < 6; ++i)
        #pragma unroll
        for (int j = 0; j < 6; ++j) {
            if (i <= j) {
                float acc = 0.0f;
                #pragma unroll
                for (int kk = 0; kk < 6; ++kk)
                    acc = fmaf(L[kk][i], N[kk][j], acc);
                Ms[i][j] = acc; Ms[j][i] = acc;
            }
        }

    // ---- Jacobi (parallel ordering); eigenvector of LARGEST eigenvalue ----
    float W[6][6];
    jacobi6f(Ms, W, 5);
    float l2max = Ms[0][0];
    int imax = 0;
    #pragma unroll
    for (int i = 1; i < 6; ++i) {
        if (Ms[i][i] > l2max) { l2max = Ms[i][i]; imax = i; }
    }
    float y6[6];
    #pragma unroll
    for (int i = 0; i < 6; ++i) {
        float acc = 0.0f;
        #pragma unroll
        for (int jj = 0; jj < 6; ++jj) acc += (jj == imax) ? W[i][jj] : 0.0f;
        y6[i] = acc;
    }

    // ---- v = L^{-T} y (back-substitution) ----
    float v5 = y6[5] * __builtin_amdgcn_rcpf(L[5][5]);
    float v4 = (y6[4] - L[5][4]*v5) * __builtin_amdgcn_rcpf(L[4][4]);
    float v3 = (y6[3] - L[4][3]*v4 - L[5][3]*v5) * __builtin_amdgcn_rcpf(L[3][3]);
    float v2 = (y6[2] - L[3][2]*v3 - L[4][2]*v4 - L[5][2]*v5) * __builtin_amdgcn_rcpf(L[2][2]);
    float v1 = (y6[1] - L[2][1]*v2 - L[3][1]*v3 - L[4][1]*v4 - L[5][1]*v5) * __builtin_amdgcn_rcpf(L[1][1]);
    float v0 = (y6[0] - L[1][0]*v1 - L[2][0]*v2 - L[3][0]*v3 - L[4][0]*v4 - L[5][0]*v5) * __builtin_amdgcn_rcpf(L[0][0]);

    // ---- 3x3 symmetric eigenvalue ratio (closed form, f32) ----
    float a = v0, b = v1, cc = v2, d = v3, e = v4, f = v5;
    float ev0, ev1, ev2;
    float off = d * d + e * e + f * f;
    if (off == 0.0f) {
        ev0 = a; ev1 = b; ev2 = cc;
    } else {
        float q = (a + b + cc) * (1.0f / 3.0f);
        float p2 = (a-q)*(a-q) + (b-q)*(b-q) + (cc-q)*(cc-q) + 2.0f * off;
        float p = sqrtf(p2 * (1.0f / 6.0f));
        float ip = __builtin_amdgcn_rcpf(p);
        float b00 = (a - q) * ip, b11 = (b - q) * ip, b22 = (cc - q) * ip;
        float b01 = d * ip, b02 = e * ip, b12 = f * ip;
        float detB = b00 * (b11 * b22 - b12 * b12)
                   - b01 * (b01 * b22 - b12 * b02)
                   + b02 * (b01 * b12 - b11 * b02);
        float rr = 0.5f * detB;
        rr = fminf(1.0f, fmaxf(-1.0f, rr));
        float phi = acosf(rr) * (1.0f / 3.0f);
        ev0 = q + 2.0f * p * cosf(phi);
        ev2 = q + 2.0f * p * cosf(phi + (float)(2.0 * M_PI / 3.0));
        ev1 = 3.0f * q - ev0 - ev2;
    }
    float A0 = fabsf(ev0), A1 = fabsf(ev1), A2 = fabsf(ev2);
    float mx = fmaxf(A0, fmaxf(A1, A2));
    float mn = fminf(A0, fminf(A1, A2));
    float simi = sqrtf(fmaxf(mn, 1e-9f) / fmaxf(mx, 1e-9f));

    out[pi * 128 + pj] = simi;
}

extern "C" void kernel_launch(void* const* d_in, const int* in_sizes, int n_in,
                              void* d_out, int out_size, void* d_ws, size_t ws_size,
                              hipStream_t stream) {
    const float* depth = (const float*)d_in[0];
    float* out = (float*)d_out;
    curv_kernel<<<dim3(256), dim3(64), 0, stream>>>(depth, out);
}

// Round 5
// 26.161 us; speedup vs baseline: 4.1676x; 1.2613x over previous
//
#include <hip/hip_runtime.h>
#include <math.h>

#ifndef M_PI
#define M_PI 3.14159265358979323846
#endif

#define IMGW 1024
#define SIDX(m,n) ((m)*9 - ((m)*((m)-1))/2 + ((n)-(m)))

// Masked pure-xy moments for the 4 pad patterns (none/top/left/corner).
// Order: u4, v4, u2v2, u3v, uv3, u3, v3, u2v, uv2, u2, v2, uv, u, v
__device__ __constant__ float PURE[4][14] = {
    {3616.f, 3616.f, 1936.f, 256.f, 256.f, -512.f, -512.f, -176.f, -176.f, 352.f, 352.f, 16.f, -32.f, -32.f},
    {3164.f, 1568.f, 1232.f,   0.f,   0.f, -448.f,    0.f,    0.f, -112.f, 308.f, 224.f,  0.f, -28.f,   0.f},
    {1568.f, 3164.f, 1232.f,   0.f,   0.f,    0.f, -448.f, -112.f,    0.f, 224.f, 308.f,  0.f,   0.f, -28.f},
    {1372.f, 1372.f,  784.f,   0.f,   0.f,    0.f,    0.f,    0.f,    0.f, 196.f, 196.f,  0.f,   0.f,   0.f}
};
enum { P_U4, P_V4, P_U2V2, P_U3V, P_UV3, P_U3, P_V3, P_U2V, P_UV2, P_U2, P_V2, P_UV, P_U, P_V };

// ---------------- Jacobi: parallel-ordered (3 disjoint rotations/round) ----
template<int P, int Q>
__device__ __forceinline__ void jangle(const float (&A)[6][6], float& c, float& s) {
    float apq = A[P][Q];
    float tau = (A[Q][Q] - A[P][P]) * __builtin_amdgcn_rcpf(2.0f * apq);
    float t = copysignf(__builtin_amdgcn_rcpf(fabsf(tau) + sqrtf(fmaf(tau, tau, 1.0f))), tau);
    t = (fabsf(apq) > 1e-20f) ? t : 0.0f;
    c = __builtin_amdgcn_rsqf(fmaf(t, t, 1.0f));
    s = t * c;
}

template<int P, int Q>
__device__ __forceinline__ void japply(float (&A)[6][6], float (&V)[6][6], float c, float s) {
    #pragma unroll
    for (int kk = 0; kk < 6; ++kk) {
        float akp = A[kk][P], akq = A[kk][Q];
        A[kk][P] = fmaf(c, akp, -s * akq);
        A[kk][Q] = fmaf(s, akp, c * akq);
    }
    #pragma unroll
    for (int kk = 0; kk < 6; ++kk) {
        float apk = A[P][kk], aqk = A[Q][kk];
        A[P][kk] = fmaf(c, apk, -s * aqk);
        A[Q][kk] = fmaf(s, apk, c * aqk);
    }
    #pragma unroll
    for (int kk = 0; kk < 6; ++kk) {
        float vkp = V[kk][P], vkq = V[kk][Q];
        V[kk][P] = fmaf(c, vkp, -s * vkq);
        V[kk][Q] = fmaf(s, vkp, c * vkq);
    }
}

template<int P0,int Q0,int P1,int Q1,int P2,int Q2>
__device__ __forceinline__ void jround3(float (&A)[6][6], float (&V)[6][6]) {
    float c0,s0,c1,s1,c2,s2;
    jangle<P0,Q0>(A, c0, s0);
    jangle<P1,Q1>(A, c1, s1);
    jangle<P2,Q2>(A, c2, s2);
    japply<P0,Q0>(A, V, c0, s0);
    japply<P1,Q1>(A, V, c1, s1);
    japply<P2,Q2>(A, V, c2, s2);
}

__device__ __forceinline__ void jacobi6f(float (&A)[6][6], float (&V)[6][6], int sweeps) {
    #pragma unroll
    for (int i = 0; i < 6; ++i)
        #pragma unroll
        for (int j = 0; j < 6; ++j)
            V[i][j] = (i == j) ? 1.0f : 0.0f;
    for (int sw = 0; sw < sweeps; ++sw) {
        jround3<0,5, 1,4, 2,3>(A, V);
        jround3<0,4, 3,5, 1,2>(A, V);
        jround3<0,3, 2,4, 1,5>(A, V);
        jround3<0,2, 1,3, 4,5>(A, V);
        jround3<0,1, 2,5, 3,4>(A, V);
    }
}

// ---------------- Schur complement S -> A6 (precision T) -------------------
template<typename T>
__device__ __forceinline__ void schur6(const T (&S)[45], float (&A6)[6][6]) {
    T g00 = S[SIDX(6,6)], g01 = S[SIDX(6,7)], g02 = S[SIDX(6,8)];
    T g11 = S[SIDX(7,7)], g12 = S[SIDX(7,8)], g22 = S[SIDX(8,8)];
    T c00 = g11 * g22 - g12 * g12;
    T c01 = g02 * g12 - g01 * g22;
    T c02 = g01 * g12 - g02 * g11;
    T det = g00 * c00 + g01 * c01 + g02 * c02;
    T invdet = (T)1 / det;
    T gi00 = c00 * invdet, gi01 = c01 * invdet, gi02 = c02 * invdet;
    T gi11 = (g00 * g22 - g02 * g02) * invdet;
    T gi12 = (g01 * g02 - g00 * g12) * invdet;
    T gi22 = (g00 * g11 - g01 * g01) * invdet;

    T B0[6], B1[6], B2[6], T0[6], T1[6], T2[6];
    #pragma unroll
    for (int m = 0; m < 6; ++m) {
        B0[m] = S[SIDX(m,6)]; B1[m] = S[SIDX(m,7)]; B2[m] = S[SIDX(m,8)];
    }
    #pragma unroll
    for (int m = 0; m < 6; ++m) {
        T0[m] = gi00 * B0[m] + gi01 * B1[m] + gi02 * B2[m];
        T1[m] = gi01 * B0[m] + gi11 * B1[m] + gi12 * B2[m];
        T2[m] = gi02 * B0[m] + gi12 * B1[m] + gi22 * B2[m];
    }
    #pragma unroll
    for (int m = 0; m < 6; ++m)
        #pragma unroll
        for (int n = m; n < 6; ++n) {
            T val = S[SIDX(m,n)] - (B0[m] * T0[n] + B1[m] * T1[n] + B2[m] * T2[n]);
            A6[m][n] = (float)val; A6[n][m] = (float)val;
        }
}

// 20 depth-weighted moments from a register-resident 8x8 window (wv pre-masked)
struct Wm {
    float W1_1,W1_u,W1_v,W1_uu,W1_uv,W1_vv,W1_u3,W1_uuv,W1_uvv,W1_v3;
    float W2_1,W2_u,W2_v,W2_uu,W2_uv,W2_vv;
    float W3_1,W3_u,W3_v,W4_1;
};

__device__ __forceinline__ void accum_moments(const float (&wv)[64], Wm& W) {
    W = {};
    #pragma unroll
    for (int r = 0; r < 8; ++r) {
        #pragma unroll
        for (int c = 0; c < 8; ++c) {
            float w = wv[r * 8 + c];
            const float U = (float)(c - 4);
            const float Vv = (float)(r - 4);
            float w2 = w * w, w3 = w2 * w, w4 = w2 * w2;
            W.W1_1 += w;
            W.W1_u   = fmaf(U, w, W.W1_u);
            W.W1_v   = fmaf(Vv, w, W.W1_v);
            W.W1_uu  = fmaf(U * U, w, W.W1_uu);
            W.W1_uv  = fmaf(U * Vv, w, W.W1_uv);
            W.W1_vv  = fmaf(Vv * Vv, w, W.W1_vv);
            W.W1_u3  = fmaf(U * U * U, w, W.W1_u3);
            W.W1_uuv = fmaf(U * U * Vv, w, W.W1_uuv);
            W.W1_uvv = fmaf(U * Vv * Vv, w, W.W1_uvv);
            W.W1_v3  = fmaf(Vv * Vv * Vv, w, W.W1_v3);
            W.W2_1 += w2;
            W.W2_u   = fmaf(U, w2, W.W2_u);
            W.W2_v   = fmaf(Vv, w2, W.W2_v);
            W.W2_uu  = fmaf(U * U, w2, W.W2_uu);
            W.W2_uv  = fmaf(U * Vv, w2, W.W2_uv);
            W.W2_vv  = fmaf(Vv * Vv, w2, W.W2_vv);
            W.W3_1 += w3;
            W.W3_u   = fmaf(U, w3, W.W3_u);
            W.W3_v   = fmaf(Vv, w3, W.W3_v);
            W.W4_1 += w4;
        }
    }
}

__global__ __launch_bounds__(64, 1)
void curv_kernel(const float* __restrict__ depth, float* __restrict__ out) {
    unsigned k = blockIdx.x * 64u + threadIdx.x;
    if (k >= 16384u) return;

    // Partition: 252 exact waves of interior (excl. (127,127)); 4 exact waves
    // of boundary + (127,127). No wave mixes the two code paths.
    int pi, pj;
    bool boundary;
    if (k < 16128u) {
        pi = 1 + (int)(k / 127u);
        pj = 1 + (int)(k % 127u);
        boundary = false;
    } else {
        unsigned b = k - 16128u;        // 0..255
        if (b < 128u)      { pi = 0; pj = (int)b; }
        else if (b < 255u) { pi = (int)(b - 127u); pj = 0; }
        else               { pi = 127; pj = 127; }
        boundary = true;
    }

    float A6[6][6];

    if (!boundary) {
        const float* pbase = depth + (pi * 8 - 1) * IMGW + (pj * 8 - 1);
        float d36 = pbase[4 * IMGW + 4];
        // load all 64 pixels first (independent loads -> one latency exposure)
        float wv[64];
        #pragma unroll
        for (int r = 0; r < 8; ++r)
            #pragma unroll
            for (int c = 0; c < 8; ++c)
                wv[r * 8 + c] = pbase[r * IMGW + c];
        #pragma unroll
        for (int i = 0; i < 64; ++i) wv[i] -= d36;

        Wm W;
        accum_moments(wv, W);

        float S[45];
        S[SIDX(0,0)] = 3616.0f;   S[SIDX(0,1)] = 1936.0f;  S[SIDX(0,2)] = W.W2_uu;
        S[SIDX(0,3)] = 512.0f;    S[SIDX(0,4)] = 2.0f*W.W1_u3; S[SIDX(0,5)] = 2.0f*W.W1_uuv;
        S[SIDX(0,6)] = -1024.0f;  S[SIDX(0,7)] = -352.0f;  S[SIDX(0,8)] = 2.0f*W.W1_uu;
        S[SIDX(1,1)] = 3616.0f;   S[SIDX(1,2)] = W.W2_vv;  S[SIDX(1,3)] = 512.0f;
        S[SIDX(1,4)] = 2.0f*W.W1_uvv; S[SIDX(1,5)] = 2.0f*W.W1_v3;
        S[SIDX(1,6)] = -352.0f;   S[SIDX(1,7)] = -1024.0f; S[SIDX(1,8)] = 2.0f*W.W1_vv;
        S[SIDX(2,2)] = W.W4_1;    S[SIDX(2,3)] = 2.0f*W.W2_uv;
        S[SIDX(2,4)] = 2.0f*W.W3_u; S[SIDX(2,5)] = 2.0f*W.W3_v;
        S[SIDX(2,6)] = 2.0f*W.W2_u; S[SIDX(2,7)] = 2.0f*W.W2_v; S[SIDX(2,8)] = 2.0f*W.W3_1;
        S[SIDX(3,3)] = 7744.0f;   S[SIDX(3,4)] = 4.0f*W.W1_uuv; S[SIDX(3,5)] = 4.0f*W.W1_uvv;
        S[SIDX(3,6)] = -704.0f;   S[SIDX(3,7)] = -704.0f;  S[SIDX(3,8)] = 4.0f*W.W1_uv;
        S[SIDX(4,4)] = 4.0f*W.W2_uu; S[SIDX(4,5)] = 4.0f*W.W2_uv;
        S[SIDX(4,6)] = 4.0f*W.W1_uu; S[SIDX(4,7)] = 4.0f*W.W1_uv; S[SIDX(4,8)] = 4.0f*W.W2_u;
        S[SIDX(5,5)] = 4.0f*W.W2_vv;
        S[SIDX(5,6)] = 4.0f*W.W1_uv; S[SIDX(5,7)] = 4.0f*W.W1_vv; S[SIDX(5,8)] = 4.0f*W.W2_v;
        S[SIDX(6,6)] = 1408.0f;   S[SIDX(6,7)] = 64.0f;    S[SIDX(6,8)] = 4.0f*W.W1_u;
        S[SIDX(7,7)] = 1408.0f;   S[SIDX(7,8)] = 4.0f*W.W1_v;
        S[SIDX(8,8)] = 4.0f*W.W2_1;
        schur6<float>(S, A6);
    } else {
        bool top = (pi == 0), left = (pj == 0);
        int pat = (top ? 1 : 0) + (left ? 2 : 0);
        int baseR = pi * 8 - 1, baseC = pj * 8 - 1;
        float d36 = depth[(pi * 8 + 3) * IMGW + (pj * 8 + 3)];
        // load all 64 (clamped addresses), then mask pads to wv=0
        float wv[64];
        #pragma unroll
        for (int r = 0; r < 8; ++r) {
            int ir = max(baseR + r, 0);
            #pragma unroll
            for (int c = 0; c < 8; ++c) {
                int ic = max(baseC + c, 0);
                wv[r * 8 + c] = depth[ir * IMGW + ic];
            }
        }
        #pragma unroll
        for (int r = 0; r < 8; ++r)
            #pragma unroll
            for (int c = 0; c < 8; ++c) {
                bool pad = (top && r == 0) || (left && c == 0);
                wv[r * 8 + c] = pad ? 0.0f : (wv[r * 8 + c] - d36);
            }

        Wm W;
        accum_moments(wv, W);

        const float* P = PURE[pat];
        float S32[45];
        S32[SIDX(0,0)] = P[P_U4];    S32[SIDX(0,1)] = P[P_U2V2]; S32[SIDX(0,2)] = W.W2_uu;
        S32[SIDX(0,3)] = 2.0f*P[P_U3V]; S32[SIDX(0,4)] = 2.0f*W.W1_u3; S32[SIDX(0,5)] = 2.0f*W.W1_uuv;
        S32[SIDX(0,6)] = 2.0f*P[P_U3]; S32[SIDX(0,7)] = 2.0f*P[P_U2V]; S32[SIDX(0,8)] = 2.0f*W.W1_uu;
        S32[SIDX(1,1)] = P[P_V4];    S32[SIDX(1,2)] = W.W2_vv;   S32[SIDX(1,3)] = 2.0f*P[P_UV3];
        S32[SIDX(1,4)] = 2.0f*W.W1_uvv; S32[SIDX(1,5)] = 2.0f*W.W1_v3;
        S32[SIDX(1,6)] = 2.0f*P[P_UV2]; S32[SIDX(1,7)] = 2.0f*P[P_V3]; S32[SIDX(1,8)] = 2.0f*W.W1_vv;
        S32[SIDX(2,2)] = W.W4_1;     S32[SIDX(2,3)] = 2.0f*W.W2_uv;
        S32[SIDX(2,4)] = 2.0f*W.W3_u; S32[SIDX(2,5)] = 2.0f*W.W3_v;
        S32[SIDX(2,6)] = 2.0f*W.W2_u; S32[SIDX(2,7)] = 2.0f*W.W2_v; S32[SIDX(2,8)] = 2.0f*W.W3_1;
        S32[SIDX(3,3)] = 4.0f*P[P_U2V2]; S32[SIDX(3,4)] = 4.0f*W.W1_uuv; S32[SIDX(3,5)] = 4.0f*W.W1_uvv;
        S32[SIDX(3,6)] = 4.0f*P[P_U2V]; S32[SIDX(3,7)] = 4.0f*P[P_UV2]; S32[SIDX(3,8)] = 4.0f*W.W1_uv;
        S32[SIDX(4,4)] = 4.0f*W.W2_uu; S32[SIDX(4,5)] = 4.0f*W.W2_uv;
        S32[SIDX(4,6)] = 4.0f*W.W1_uu; S32[SIDX(4,7)] = 4.0f*W.W1_uv; S32[SIDX(4,8)] = 4.0f*W.W2_u;
        S32[SIDX(5,5)] = 4.0f*W.W2_vv;
        S32[SIDX(5,6)] = 4.0f*W.W1_uv; S32[SIDX(5,7)] = 4.0f*W.W1_vv; S32[SIDX(5,8)] = 4.0f*W.W2_v;
        S32[SIDX(6,6)] = 4.0f*P[P_U2]; S32[SIDX(6,7)] = 4.0f*P[P_UV]; S32[SIDX(6,8)] = 4.0f*W.W1_u;
        S32[SIDX(7,7)] = 4.0f*P[P_V2]; S32[SIDX(7,8)] = 4.0f*W.W1_v;
        S32[SIDX(8,8)] = 4.0f*W.W2_1;

        // exact f64 rank-1 far-point update for the coincident pad pixels
        double m = (double)((top ? 8 : 0) + (left ? 8 : 0) - ((top && left) ? 1 : 0));
        double xf = -(double)(pj * 8 + 3);
        double yf = -(double)(pi * 8 + 3);
        double df = -(double)d36;
        double d9f[9];
        d9f[0] = xf * xf; d9f[1] = yf * yf; d9f[2] = df * df;
        d9f[3] = 2.0 * xf * yf; d9f[4] = 2.0 * xf * df; d9f[5] = 2.0 * yf * df;
        d9f[6] = 2.0 * xf; d9f[7] = 2.0 * yf; d9f[8] = 2.0 * df;
        double S64[45];
        #pragma unroll
        for (int mm = 0; mm < 9; ++mm)
            #pragma unroll
            for (int nn = mm; nn < 9; ++nn)
                S64[SIDX(mm,nn)] = (double)S32[SIDX(mm,nn)] + m * d9f[mm] * d9f[nn];
        schur6<double>(S64, A6);
    }

    // ---- Cholesky A + ridge = L L^T ----
    float tr = A6[0][0] + A6[1][1] + A6[2][2] + A6[3][3] + A6[4][4] + A6[5][5];
    float ridge = 1e-6f * tr + 1e-30f;
    float dfloor = 1e-12f * tr + 1e-30f;
    float L[6][6];
    #pragma unroll
    for (int i = 0; i < 6; ++i)
        #pragma unroll
        for (int j = 0; j < 6; ++j)
            L[i][j] = 0.0f;
    #pragma unroll
    for (int j = 0; j < 6; ++j) {
        float d = A6[j][j] + ridge;
        #pragma unroll
        for (int kk = 0; kk < 6; ++kk)
            if (kk < j) d = fmaf(-L[j][kk], L[j][kk], d);
        d = fmaxf(d, dfloor);
        float sd = sqrtf(d);
        float isd = __builtin_amdgcn_rcpf(sd);
        L[j][j] = sd;
        #pragma unroll
        for (int i = 0; i < 6; ++i) {
            if (i > j) {
                float v = A6[i][j];
                #pragma unroll
                for (int kk = 0; kk < 6; ++kk)
                    if (kk < j) v = fmaf(-L[i][kk], L[j][kk], v);
                L[i][j] = v * isd;
            }
        }
    }

    // ---- Ms = L^T Cinv L; Cinv = blockdiag((J-I)/2, -I/4) ----
    float N[6][6];
    #pragma unroll
    for (int j = 0; j < 6; ++j) {
        N[0][j] = 0.5f * (L[1][j] + L[2][j]);
        N[1][j] = 0.5f * (L[0][j] + L[2][j]);
        N[2][j] = 0.5f * (L[0][j] + L[1][j]);
        N[3][j] = -0.25f * L[3][j];
        N[4][j] = -0.25f * L[4][j];
        N[5][j] = -0.25f * L[5][j];
    }
    float Ms[6][6];
    #pragma unroll
    for (int i = 0; i < 6; ++i)
        #pragma unroll
        for (int j = 0; j < 6; ++j) {
            if (i <= j) {
                float acc = 0.0f;
                #pragma unroll
                for (int kk = 0; kk < 6; ++kk)
                    acc = fmaf(L[kk][i], N[kk][j], acc);
                Ms[i][j] = acc; Ms[j][i] = acc;
            }
        }

    // ---- Jacobi (parallel ordering); eigenvector of LARGEST eigenvalue ----
    float W6[6][6];
    jacobi6f(Ms, W6, 5);
    float l2max = Ms[0][0];
    int imax = 0;
    #pragma unroll
    for (int i = 1; i < 6; ++i) {
        if (Ms[i][i] > l2max) { l2max = Ms[i][i]; imax = i; }
    }
    float y6[6];
    #pragma unroll
    for (int i = 0; i < 6; ++i) {
        float acc = 0.0f;
        #pragma unroll
        for (int jj = 0; jj < 6; ++jj) acc += (jj == imax) ? W6[i][jj] : 0.0f;
        y6[i] = acc;
    }

    // ---- v = L^{-T} y (back-substitution) ----
    float v5 = y6[5] * __builtin_amdgcn_rcpf(L[5][5]);
    float v4 = (y6[4] - L[5][4]*v5) * __builtin_amdgcn_rcpf(L[4][4]);
    float v3 = (y6[3] - L[4][3]*v4 - L[5][3]*v5) * __builtin_amdgcn_rcpf(L[3][3]);
    float v2 = (y6[2] - L[3][2]*v3 - L[4][2]*v4 - L[5][2]*v5) * __builtin_amdgcn_rcpf(L[2][2]);
    float v1 = (y6[1] - L[2][1]*v2 - L[3][1]*v3 - L[4][1]*v4 - L[5][1]*v5) * __builtin_amdgcn_rcpf(L[1][1]);
    float v0 = (y6[0] - L[1][0]*v1 - L[2][0]*v2 - L[3][0]*v3 - L[4][0]*v4 - L[5][0]*v5) * __builtin_amdgcn_rcpf(L[0][0]);

    // ---- 3x3 symmetric eigenvalue ratio (closed form, f32) ----
    float a = v0, b = v1, cc = v2, d = v3, e = v4, f = v5;
    float ev0, ev1, ev2;
    float off = d * d + e * e + f * f;
    if (off == 0.0f) {
        ev0 = a; ev1 = b; ev2 = cc;
    } else {
        float q = (a + b + cc) * (1.0f / 3.0f);
        float p2 = (a-q)*(a-q) + (b-q)*(b-q) + (cc-q)*(cc-q) + 2.0f * off;
        float p = sqrtf(p2 * (1.0f / 6.0f));
        float ip = __builtin_amdgcn_rcpf(p);
        float b00 = (a - q) * ip, b11 = (b - q) * ip, b22 = (cc - q) * ip;
        float b01 = d * ip, b02 = e * ip, b12 = f * ip;
        float detB = b00 * (b11 * b22 - b12 * b12)
                   - b01 * (b01 * b22 - b12 * b02)
                   + b02 * (b01 * b12 - b11 * b02);
        float rr = 0.5f * detB;
        rr = fminf(1.0f, fmaxf(-1.0f, rr));
        float phi = acosf(rr) * (1.0f / 3.0f);
        ev0 = q + 2.0f * p * cosf(phi);
        ev2 = q + 2.0f * p * cosf(phi + (float)(2.0 * M_PI / 3.0));
        ev1 = 3.0f * q - ev0 - ev2;
    }
    float A0 = fabsf(ev0), A1 = fabsf(ev1), A2 = fabsf(ev2);
    float mx = fmaxf(A0, fmaxf(A1, A2));
    float mn = fminf(A0, fminf(A1, A2));
    float simi = sqrtf(fmaxf(mn, 1e-9f) / fmaxf(mx, 1e-9f));

    out[pi * 128 + pj] = simi;
}

extern "C" void kernel_launch(void* const* d_in, const int* in_sizes, int n_in,
                              void* d_out, int out_size, void* d_ws, size_t ws_size,
                              hipStream_t stream) {
    const float* depth = (const float*)d_in[0];
    float* out = (float*)d_out;
    curv_kernel<<<dim3(256), dim3(64), 0, stream>>>(depth, out);
}

// Round 6
// 19.572 us; speedup vs baseline: 5.5707x; 1.3367x over previous
//
#include <hip/hip_runtime.h>
#include <math.h>

#ifndef M_PI
#define M_PI 3.14159265358979323846
#endif

#define IMGW 1024
#define SIDX(m,n) ((m)*9 - ((m)*((m)-1))/2 + ((n)-(m)))

// upper-triangle index for 6x6 symmetric (21 entries), mirror-safe
__device__ __host__ constexpr int ut(int i, int j) {
    return (i <= j) ? (i * 6 - (i * (i - 1)) / 2 + (j - i))
                    : (j * 6 - (j * (j - 1)) / 2 + (i - j));
}

// Masked pure-xy moments for the 4 pad patterns (none/top/left/corner).
// Order: u4, v4, u2v2, u3v, uv3, u3, v3, u2v, uv2, u2, v2, uv, u, v
__device__ __constant__ float PURE[4][14] = {
    {3616.f, 3616.f, 1936.f, 256.f, 256.f, -512.f, -512.f, -176.f, -176.f, 352.f, 352.f, 16.f, -32.f, -32.f},
    {3164.f, 1568.f, 1232.f,   0.f,   0.f, -448.f,    0.f,    0.f, -112.f, 308.f, 224.f,  0.f, -28.f,   0.f},
    {1568.f, 3164.f, 1232.f,   0.f,   0.f,    0.f, -448.f, -112.f,    0.f, 224.f, 308.f,  0.f,   0.f, -28.f},
    {1372.f, 1372.f,  784.f,   0.f,   0.f,    0.f,    0.f,    0.f,    0.f, 196.f, 196.f,  0.f,   0.f,   0.f}
};
enum { P_U4, P_V4, P_U2V2, P_U3V, P_UV3, P_U3, P_V3, P_U2V, P_UV2, P_U2, P_V2, P_UV, P_U, P_V };

// ------------- symmetric-storage Jacobi, parallel-ordered rounds -----------
template<int P, int Q>
__device__ __forceinline__ void jangle(const float (&A)[21], float& c, float& s, float& t) {
    float apq = A[ut(P,Q)];
    float tau = (A[ut(Q,Q)] - A[ut(P,P)]) * __builtin_amdgcn_rcpf(2.0f * apq);
    float tt = copysignf(__builtin_amdgcn_rcpf(fabsf(tau) + sqrtf(fmaf(tau, tau, 1.0f))), tau);
    t = (fabsf(apq) > 1e-20f) ? tt : 0.0f;
    c = __builtin_amdgcn_rsqf(fmaf(t, t, 1.0f));
    s = t * c;
}

template<int P, int Q>
__device__ __forceinline__ void japply(float (&A)[21], float (&V)[6][6], float c, float s, float t) {
    #pragma unroll
    for (int k = 0; k < 6; ++k) {
        if (k != P && k != Q) {
            float akp = A[ut(k,P)], akq = A[ut(k,Q)];
            A[ut(k,P)] = fmaf(c, akp, -s * akq);
            A[ut(k,Q)] = fmaf(s, akp, c * akq);
        }
    }
    float apq = A[ut(P,Q)];
    A[ut(P,P)] = fmaf(-t, apq, A[ut(P,P)]);
    A[ut(Q,Q)] = fmaf( t, apq, A[ut(Q,Q)]);
    A[ut(P,Q)] = 0.0f;
    #pragma unroll
    for (int k = 0; k < 6; ++k) {
        float vkp = V[k][P], vkq = V[k][Q];
        V[k][P] = fmaf(c, vkp, -s * vkq);
        V[k][Q] = fmaf(s, vkp, c * vkq);
    }
}

template<int P0,int Q0,int P1,int Q1,int P2,int Q2>
__device__ __forceinline__ void jround3(float (&A)[21], float (&V)[6][6]) {
    float c0,s0,t0,c1,s1,t1,c2,s2,t2;
    jangle<P0,Q0>(A, c0, s0, t0);   // disjoint pivots: 3 independent chains
    jangle<P1,Q1>(A, c1, s1, t1);
    jangle<P2,Q2>(A, c2, s2, t2);
    japply<P0,Q0>(A, V, c0, s0, t0);
    japply<P1,Q1>(A, V, c1, s1, t1);
    japply<P2,Q2>(A, V, c2, s2, t2);
}

__device__ __forceinline__ void jacobi6f(float (&A)[21], float (&V)[6][6], int sweeps) {
    #pragma unroll
    for (int i = 0; i < 6; ++i)
        #pragma unroll
        for (int j = 0; j < 6; ++j)
            V[i][j] = (i == j) ? 1.0f : 0.0f;
    for (int sw = 0; sw < sweeps; ++sw) {
        jround3<0,5, 1,4, 2,3>(A, V);
        jround3<0,4, 3,5, 1,2>(A, V);
        jround3<0,3, 2,4, 1,5>(A, V);
        jround3<0,2, 1,3, 4,5>(A, V);
        jround3<0,1, 2,5, 3,4>(A, V);
    }
}

// ---------------- Schur complement S -> A6 (precision T) -------------------
template<typename T>
__device__ __forceinline__ void schur6(const T (&S)[45], float (&A6)[6][6]) {
    T g00 = S[SIDX(6,6)], g01 = S[SIDX(6,7)], g02 = S[SIDX(6,8)];
    T g11 = S[SIDX(7,7)], g12 = S[SIDX(7,8)], g22 = S[SIDX(8,8)];
    T c00 = g11 * g22 - g12 * g12;
    T c01 = g02 * g12 - g01 * g22;
    T c02 = g01 * g12 - g02 * g11;
    T det = g00 * c00 + g01 * c01 + g02 * c02;
    T invdet = (T)1 / det;
    T gi00 = c00 * invdet, gi01 = c01 * invdet, gi02 = c02 * invdet;
    T gi11 = (g00 * g22 - g02 * g02) * invdet;
    T gi12 = (g01 * g02 - g00 * g12) * invdet;
    T gi22 = (g00 * g11 - g01 * g01) * invdet;

    T B0[6], B1[6], B2[6], T0[6], T1[6], T2[6];
    #pragma unroll
    for (int m = 0; m < 6; ++m) {
        B0[m] = S[SIDX(m,6)]; B1[m] = S[SIDX(m,7)]; B2[m] = S[SIDX(m,8)];
    }
    #pragma unroll
    for (int m = 0; m < 6; ++m) {
        T0[m] = gi00 * B0[m] + gi01 * B1[m] + gi02 * B2[m];
        T1[m] = gi01 * B0[m] + gi11 * B1[m] + gi12 * B2[m];
        T2[m] = gi02 * B0[m] + gi12 * B1[m] + gi22 * B2[m];
    }
    #pragma unroll
    for (int m = 0; m < 6; ++m)
        #pragma unroll
        for (int n = m; n < 6; ++n) {
            T val = S[SIDX(m,n)] - (B0[m] * T0[n] + B1[m] * T1[n] + B2[m] * T2[n]);
            A6[m][n] = (float)val; A6[n][m] = (float)val;
        }
}

// 19 depth-weighted moments from a register-resident 8x8 window (pre-masked)
struct Wm {
    float W1_u,W1_v,W1_uu,W1_uv,W1_vv,W1_u3,W1_uuv,W1_uvv,W1_v3;
    float W2_1,W2_u,W2_v,W2_uu,W2_uv,W2_vv;
    float W3_1,W3_u,W3_v,W4_1;
};

__device__ __forceinline__ void accum_moments(const float (&wv)[64], Wm& W) {
    W = {};
    #pragma unroll
    for (int r = 0; r < 8; ++r) {
        #pragma unroll
        for (int c = 0; c < 8; ++c) {
            float w = wv[r * 8 + c];
            const float U = (float)(c - 4);
            const float Vv = (float)(r - 4);
            float w2 = w * w, w3 = w2 * w, w4 = w2 * w2;
            W.W1_u   = fmaf(U, w, W.W1_u);
            W.W1_v   = fmaf(Vv, w, W.W1_v);
            W.W1_uu  = fmaf(U * U, w, W.W1_uu);
            W.W1_uv  = fmaf(U * Vv, w, W.W1_uv);
            W.W1_vv  = fmaf(Vv * Vv, w, W.W1_vv);
            W.W1_u3  = fmaf(U * U * U, w, W.W1_u3);
            W.W1_uuv = fmaf(U * U * Vv, w, W.W1_uuv);
            W.W1_uvv = fmaf(U * Vv * Vv, w, W.W1_uvv);
            W.W1_v3  = fmaf(Vv * Vv * Vv, w, W.W1_v3);
            W.W2_1 += w2;
            W.W2_u   = fmaf(U, w2, W.W2_u);
            W.W2_v   = fmaf(Vv, w2, W.W2_v);
            W.W2_uu  = fmaf(U * U, w2, W.W2_uu);
            W.W2_uv  = fmaf(U * Vv, w2, W.W2_uv);
            W.W2_vv  = fmaf(Vv * Vv, w2, W.W2_vv);
            W.W3_1 += w3;
            W.W3_u   = fmaf(U, w3, W.W3_u);
            W.W3_v   = fmaf(Vv, w3, W.W3_v);
            W.W4_1 += w4;
        }
    }
}

__global__ __launch_bounds__(64, 1)
void curv_kernel(const float* __restrict__ depth, float* __restrict__ out) {
    unsigned k = blockIdx.x * 64u + threadIdx.x;
    if (k >= 16384u) return;

    // Partition: 252 exact waves interior (excl. (127,127)); 4 exact waves
    // boundary + (127,127). No wave mixes the two code paths.
    int pi, pj;
    bool boundary;
    if (k < 16128u) {
        pi = 1 + (int)(k / 127u);
        pj = 1 + (int)(k % 127u);
        boundary = false;
    } else {
        unsigned b = k - 16128u;        // 0..255
        if (b < 128u)      { pi = 0; pj = (int)b; }
        else if (b < 255u) { pi = (int)(b - 127u); pj = 0; }
        else               { pi = 127; pj = 127; }
        boundary = true;
    }

    float A6[6][6];

    if (!boundary) {
        // aligned float4 loads: 3 chunks/row covering cols 8pj-4 .. 8pj+8
        const float* rowbase = depth + (pi * 8 - 1) * IMGW + (pj * 8 - 4);
        float4 F[8][3];
        #pragma unroll
        for (int r = 0; r < 8; ++r) {
            const float4* rp = reinterpret_cast<const float4*>(rowbase + r * IMGW);
            F[r][0] = rp[0]; F[r][1] = rp[1]; F[r][2] = rp[2];
        }
        float d36 = F[4][1].w;           // row 4, col 8pj+3
        float wv[64];
        #pragma unroll
        for (int r = 0; r < 8; ++r) {
            wv[r*8+0] = F[r][0].w - d36;
            wv[r*8+1] = F[r][1].x - d36;
            wv[r*8+2] = F[r][1].y - d36;
            wv[r*8+3] = F[r][1].z - d36;
            wv[r*8+4] = F[r][1].w - d36;
            wv[r*8+5] = F[r][2].x - d36;
            wv[r*8+6] = F[r][2].y - d36;
            wv[r*8+7] = F[r][2].z - d36;
        }

        Wm W;
        accum_moments(wv, W);

        float S[45];
        S[SIDX(0,0)] = 3616.0f;   S[SIDX(0,1)] = 1936.0f;  S[SIDX(0,2)] = W.W2_uu;
        S[SIDX(0,3)] = 512.0f;    S[SIDX(0,4)] = 2.0f*W.W1_u3; S[SIDX(0,5)] = 2.0f*W.W1_uuv;
        S[SIDX(0,6)] = -1024.0f;  S[SIDX(0,7)] = -352.0f;  S[SIDX(0,8)] = 2.0f*W.W1_uu;
        S[SIDX(1,1)] = 3616.0f;   S[SIDX(1,2)] = W.W2_vv;  S[SIDX(1,3)] = 512.0f;
        S[SIDX(1,4)] = 2.0f*W.W1_uvv; S[SIDX(1,5)] = 2.0f*W.W1_v3;
        S[SIDX(1,6)] = -352.0f;   S[SIDX(1,7)] = -1024.0f; S[SIDX(1,8)] = 2.0f*W.W1_vv;
        S[SIDX(2,2)] = W.W4_1;    S[SIDX(2,3)] = 2.0f*W.W2_uv;
        S[SIDX(2,4)] = 2.0f*W.W3_u; S[SIDX(2,5)] = 2.0f*W.W3_v;
        S[SIDX(2,6)] = 2.0f*W.W2_u; S[SIDX(2,7)] = 2.0f*W.W2_v; S[SIDX(2,8)] = 2.0f*W.W3_1;
        S[SIDX(3,3)] = 7744.0f;   S[SIDX(3,4)] = 4.0f*W.W1_uuv; S[SIDX(3,5)] = 4.0f*W.W1_uvv;
        S[SIDX(3,6)] = -704.0f;   S[SIDX(3,7)] = -704.0f;  S[SIDX(3,8)] = 4.0f*W.W1_uv;
        S[SIDX(4,4)] = 4.0f*W.W2_uu; S[SIDX(4,5)] = 4.0f*W.W2_uv;
        S[SIDX(4,6)] = 4.0f*W.W1_uu; S[SIDX(4,7)] = 4.0f*W.W1_uv; S[SIDX(4,8)] = 4.0f*W.W2_u;
        S[SIDX(5,5)] = 4.0f*W.W2_vv;
        S[SIDX(5,6)] = 4.0f*W.W1_uv; S[SIDX(5,7)] = 4.0f*W.W1_vv; S[SIDX(5,8)] = 4.0f*W.W2_v;
        S[SIDX(6,6)] = 1408.0f;   S[SIDX(6,7)] = 64.0f;    S[SIDX(6,8)] = 4.0f*W.W1_u;
        S[SIDX(7,7)] = 1408.0f;   S[SIDX(7,8)] = 4.0f*W.W1_v;
        S[SIDX(8,8)] = 4.0f*W.W2_1;
        schur6<float>(S, A6);
    } else {
        bool top = (pi == 0), left = (pj == 0);
        int pat = (top ? 1 : 0) + (left ? 2 : 0);
        int baseR = pi * 8 - 1, baseC = pj * 8 - 1;
        float d36 = depth[(pi * 8 + 3) * IMGW + (pj * 8 + 3)];
        float wv[64];
        #pragma unroll
        for (int r = 0; r < 8; ++r) {
            int ir = max(baseR + r, 0);
            #pragma unroll
            for (int c = 0; c < 8; ++c) {
                int ic = max(baseC + c, 0);
                wv[r * 8 + c] = depth[ir * IMGW + ic];
            }
        }
        #pragma unroll
        for (int r = 0; r < 8; ++r)
            #pragma unroll
            for (int c = 0; c < 8; ++c) {
                bool pad = (top && r == 0) || (left && c == 0);
                wv[r * 8 + c] = pad ? 0.0f : (wv[r * 8 + c] - d36);
            }

        Wm W;
        accum_moments(wv, W);

        const float* P = PURE[pat];
        float S32[45];
        S32[SIDX(0,0)] = P[P_U4];    S32[SIDX(0,1)] = P[P_U2V2]; S32[SIDX(0,2)] = W.W2_uu;
        S32[SIDX(0,3)] = 2.0f*P[P_U3V]; S32[SIDX(0,4)] = 2.0f*W.W1_u3; S32[SIDX(0,5)] = 2.0f*W.W1_uuv;
        S32[SIDX(0,6)] = 2.0f*P[P_U3]; S32[SIDX(0,7)] = 2.0f*P[P_U2V]; S32[SIDX(0,8)] = 2.0f*W.W1_uu;
        S32[SIDX(1,1)] = P[P_V4];    S32[SIDX(1,2)] = W.W2_vv;   S32[SIDX(1,3)] = 2.0f*P[P_UV3];
        S32[SIDX(1,4)] = 2.0f*W.W1_uvv; S32[SIDX(1,5)] = 2.0f*W.W1_v3;
        S32[SIDX(1,6)] = 2.0f*P[P_UV2]; S32[SIDX(1,7)] = 2.0f*P[P_V3]; S32[SIDX(1,8)] = 2.0f*W.W1_vv;
        S32[SIDX(2,2)] = W.W4_1;     S32[SIDX(2,3)] = 2.0f*W.W2_uv;
        S32[SIDX(2,4)] = 2.0f*W.W3_u; S32[SIDX(2,5)] = 2.0f*W.W3_v;
        S32[SIDX(2,6)] = 2.0f*W.W2_u; S32[SIDX(2,7)] = 2.0f*W.W2_v; S32[SIDX(2,8)] = 2.0f*W.W3_1;
        S32[SIDX(3,3)] = 4.0f*P[P_U2V2]; S32[SIDX(3,4)] = 4.0f*W.W1_uuv; S32[SIDX(3,5)] = 4.0f*W.W1_uvv;
        S32[SIDX(3,6)] = 4.0f*P[P_U2V]; S32[SIDX(3,7)] = 4.0f*P[P_UV2]; S32[SIDX(3,8)] = 4.0f*W.W1_uv;
        S32[SIDX(4,4)] = 4.0f*W.W2_uu; S32[SIDX(4,5)] = 4.0f*W.W2_uv;
        S32[SIDX(4,6)] = 4.0f*W.W1_uu; S32[SIDX(4,7)] = 4.0f*W.W1_uv; S32[SIDX(4,8)] = 4.0f*W.W2_u;
        S32[SIDX(5,5)] = 4.0f*W.W2_vv;
        S32[SIDX(5,6)] = 4.0f*W.W1_uv; S32[SIDX(5,7)] = 4.0f*W.W1_vv; S32[SIDX(5,8)] = 4.0f*W.W2_v;
        S32[SIDX(6,6)] = 4.0f*P[P_U2]; S32[SIDX(6,7)] = 4.0f*P[P_UV]; S32[SIDX(6,8)] = 4.0f*W.W1_u;
        S32[SIDX(7,7)] = 4.0f*P[P_V2]; S32[SIDX(7,8)] = 4.0f*W.W1_v;
        S32[SIDX(8,8)] = 4.0f*W.W2_1;

        // exact f64 rank-1 far-point update for the coincident pad pixels
        double m = (double)((top ? 8 : 0) + (left ? 8 : 0) - ((top && left) ? 1 : 0));
        double xf = -(double)(pj * 8 + 3);
        double yf = -(double)(pi * 8 + 3);
        double df = -(double)d36;
        double d9f[9];
        d9f[0] = xf * xf; d9f[1] = yf * yf; d9f[2] = df * df;
        d9f[3] = 2.0 * xf * yf; d9f[4] = 2.0 * xf * df; d9f[5] = 2.0 * yf * df;
        d9f[6] = 2.0 * xf; d9f[7] = 2.0 * yf; d9f[8] = 2.0 * df;
        double S64[45];
        #pragma unroll
        for (int mm = 0; mm < 9; ++mm)
            #pragma unroll
            for (int nn = mm; nn < 9; ++nn)
                S64[SIDX(mm,nn)] = (double)S32[SIDX(mm,nn)] + m * d9f[mm] * d9f[nn];
        schur6<double>(S64, A6);
    }

    // ---- Cholesky A + ridge = L L^T ----
    float tr = A6[0][0] + A6[1][1] + A6[2][2] + A6[3][3] + A6[4][4] + A6[5][5];
    float ridge = 1e-6f * tr + 1e-30f;
    float dfloor = 1e-12f * tr + 1e-30f;
    float L[6][6];
    #pragma unroll
    for (int i = 0; i < 6; ++i)
        #pragma unroll
        for (int j = 0; j < 6; ++j)
            L[i][j] = 0.0f;
    #pragma unroll
    for (int j = 0; j < 6; ++j) {
        float d = A6[j][j] + ridge;
        #pragma unroll
        for (int kk = 0; kk < 6; ++kk)
            if (kk < j) d = fmaf(-L[j][kk], L[j][kk], d);
        d = fmaxf(d, dfloor);
        float sd = sqrtf(d);
        float isd = __builtin_amdgcn_rcpf(sd);
        L[j][j] = sd;
        #pragma unroll
        for (int i = 0; i < 6; ++i) {
            if (i > j) {
                float v = A6[i][j];
                #pragma unroll
                for (int kk = 0; kk < 6; ++kk)
                    if (kk < j) v = fmaf(-L[i][kk], L[j][kk], v);
                L[i][j] = v * isd;
            }
        }
    }

    // ---- Ms = L^T Cinv L (upper-tri storage); Cinv = blockdiag((J-I)/2, -I/4)
    float N[6][6];
    #pragma unroll
    for (int j = 0; j < 6; ++j) {
        N[0][j] = 0.5f * (L[1][j] + L[2][j]);
        N[1][j] = 0.5f * (L[0][j] + L[2][j]);
        N[2][j] = 0.5f * (L[0][j] + L[1][j]);
        N[3][j] = -0.25f * L[3][j];
        N[4][j] = -0.25f * L[4][j];
        N[5][j] = -0.25f * L[5][j];
    }
    float Ms[21];
    #pragma unroll
    for (int i = 0; i < 6; ++i)
        #pragma unroll
        for (int j = 0; j < 6; ++j) {
            if (i <= j) {
                float acc = 0.0f;
                #pragma unroll
                for (int kk = 0; kk < 6; ++kk)
                    acc = fmaf(L[kk][i], N[kk][j], acc);
                Ms[ut(i,j)] = acc;
            }
        }

    // ---- Jacobi (symmetric storage, 4 sweeps); top-eigenvalue eigenvector --
    float W6[6][6];
    jacobi6f(Ms, W6, 4);
    float l2max = Ms[ut(0,0)];
    int imax = 0;
    #pragma unroll
    for (int i = 1; i < 6; ++i) {
        float di = Ms[ut(i,i)];
        if (di > l2max) { l2max = di; imax = i; }
    }
    float y6[6];
    #pragma unroll
    for (int i = 0; i < 6; ++i) {
        float acc = 0.0f;
        #pragma unroll
        for (int jj = 0; jj < 6; ++jj) acc += (jj == imax) ? W6[i][jj] : 0.0f;
        y6[i] = acc;
    }

    // ---- v = L^{-T} y (back-substitution) ----
    float v5 = y6[5] * __builtin_amdgcn_rcpf(L[5][5]);
    float v4 = (y6[4] - L[5][4]*v5) * __builtin_amdgcn_rcpf(L[4][4]);
    float v3 = (y6[3] - L[4][3]*v4 - L[5][3]*v5) * __builtin_amdgcn_rcpf(L[3][3]);
    float v2 = (y6[2] - L[3][2]*v3 - L[4][2]*v4 - L[5][2]*v5) * __builtin_amdgcn_rcpf(L[2][2]);
    float v1 = (y6[1] - L[2][1]*v2 - L[3][1]*v3 - L[4][1]*v4 - L[5][1]*v5) * __builtin_amdgcn_rcpf(L[1][1]);
    float v0 = (y6[0] - L[1][0]*v1 - L[2][0]*v2 - L[3][0]*v3 - L[4][0]*v4 - L[5][0]*v5) * __builtin_amdgcn_rcpf(L[0][0]);

    // ---- 3x3 symmetric eigenvalue ratio (closed form, f32) ----
    float a = v0, b = v1, cc = v2, d = v3, e = v4, f = v5;
    float ev0, ev1, ev2;
    float off = d * d + e * e + f * f;
    if (off == 0.0f) {
        ev0 = a; ev1 = b; ev2 = cc;
    } else {
        float q = (a + b + cc) * (1.0f / 3.0f);
        float p2 = (a-q)*(a-q) + (b-q)*(b-q) + (cc-q)*(cc-q) + 2.0f * off;
        float p = sqrtf(p2 * (1.0f / 6.0f));
        float ip = __builtin_amdgcn_rcpf(p);
        float b00 = (a - q) * ip, b11 = (b - q) * ip, b22 = (cc - q) * ip;
        float b01 = d * ip, b02 = e * ip, b12 = f * ip;
        float detB = b00 * (b11 * b22 - b12 * b12)
                   - b01 * (b01 * b22 - b12 * b02)
                   + b02 * (b01 * b12 - b11 * b02);
        float rr = 0.5f * detB;
        rr = fminf(1.0f, fmaxf(-1.0f, rr));
        float phi = acosf(rr) * (1.0f / 3.0f);
        ev0 = q + 2.0f * p * cosf(phi);
        ev2 = q + 2.0f * p * cosf(phi + (float)(2.0 * M_PI / 3.0));
        ev1 = 3.0f * q - ev0 - ev2;
    }
    float A0 = fabsf(ev0), A1 = fabsf(ev1), A2 = fabsf(ev2);
    float mx = fmaxf(A0, fmaxf(A1, A2));
    float mn = fminf(A0, fminf(A1, A2));
    float simi = sqrtf(fmaxf(mn, 1e-9f) / fmaxf(mx, 1e-9f));

    out[pi * 128 + pj] = simi;
}

extern "C" void kernel_launch(void* const* d_in, const int* in_sizes, int n_in,
                              void* d_out, int out_size, void* d_ws, size_t ws_size,
                              hipStream_t stream) {
    const float* depth = (const float*)d_in[0];
    float* out = (float*)d_out;
    curv_kernel<<<dim3(256), dim3(64), 0, stream>>>(depth, out);
}

// Round 7
// 16.675 us; speedup vs baseline: 6.5386x; 1.1738x over previous
//
#include <hip/hip_runtime.h>
#include <math.h>

#ifndef M_PI
#define M_PI 3.14159265358979323846
#endif

#define IMGW 1024
#define SIDX(m,n) ((m)*9 - ((m)*((m)-1))/2 + ((n)-(m)))

typedef float f32x2 __attribute__((ext_vector_type(2)));

// ---- packed f32 (VOP3P) helpers: 2 FLOPs per issue slot --------------------
__device__ __forceinline__ f32x2 pk_fma(f32x2 a, f32x2 b, f32x2 c) {
    f32x2 d;
    asm("v_pk_fma_f32 %0, %1, %2, %3" : "=v"(d) : "v"(a), "v"(b), "v"(c));
    return d;
}
__device__ __forceinline__ f32x2 pk_mul(f32x2 a, f32x2 b) {
    f32x2 d;
    asm("v_pk_mul_f32 %0, %1, %2" : "=v"(d) : "v"(a), "v"(b));
    return d;
}
__device__ __forceinline__ f32x2 pk_add(f32x2 a, f32x2 b) {
    f32x2 d;
    asm("v_pk_add_f32 %0, %1, %2" : "=v"(d) : "v"(a), "v"(b));
    return d;
}

// upper-triangle index for 6x6 symmetric (21 entries), mirror-safe
__device__ __host__ constexpr int ut(int i, int j) {
    return (i <= j) ? (i * 6 - (i * (i - 1)) / 2 + (j - i))
                    : (j * 6 - (j * (j - 1)) / 2 + (i - j));
}

// Masked pure-xy moments for the 4 pad patterns (none/top/left/corner).
__device__ __constant__ float PURE[4][14] = {
    {3616.f, 3616.f, 1936.f, 256.f, 256.f, -512.f, -512.f, -176.f, -176.f, 352.f, 352.f, 16.f, -32.f, -32.f},
    {3164.f, 1568.f, 1232.f,   0.f,   0.f, -448.f,    0.f,    0.f, -112.f, 308.f, 224.f,  0.f, -28.f,   0.f},
    {1568.f, 3164.f, 1232.f,   0.f,   0.f,    0.f, -448.f, -112.f,    0.f, 224.f, 308.f,  0.f,   0.f, -28.f},
    {1372.f, 1372.f,  784.f,   0.f,   0.f,    0.f,    0.f,    0.f,    0.f, 196.f, 196.f,  0.f,   0.f,   0.f}
};
enum { P_U4, P_V4, P_U2V2, P_U3V, P_UV3, P_U3, P_V3, P_U2V, P_UV2, P_U2, P_V2, P_UV, P_U, P_V };

// ------------- symmetric-storage Jacobi, parallel-ordered rounds -----------
template<int P, int Q>
__device__ __forceinline__ void jangle(const float (&A)[21], float& c, float& s, float& t) {
    float apq = A[ut(P,Q)];
    float tau = (A[ut(Q,Q)] - A[ut(P,P)]) * __builtin_amdgcn_rcpf(2.0f * apq);
    float tt = copysignf(__builtin_amdgcn_rcpf(fabsf(tau) + sqrtf(fmaf(tau, tau, 1.0f))), tau);
    t = (fabsf(apq) > 1e-20f) ? tt : 0.0f;
    c = __builtin_amdgcn_rsqf(fmaf(t, t, 1.0f));
    s = t * c;
}

// A: scalar upper-tri update; VC: column-major packed eigvec accum (2 rows/f32x2)
template<int P, int Q>
__device__ __forceinline__ void japply(float (&A)[21], f32x2 (&VC)[6][3], float c, float s, float t) {
    #pragma unroll
    for (int k = 0; k < 6; ++k) {
        if (k != P && k != Q) {
            float akp = A[ut(k,P)], akq = A[ut(k,Q)];
            A[ut(k,P)] = fmaf(c, akp, -s * akq);
            A[ut(k,Q)] = fmaf(s, akp, c * akq);
        }
    }
    float apq = A[ut(P,Q)];
    A[ut(P,P)] = fmaf(-t, apq, A[ut(P,P)]);
    A[ut(Q,Q)] = fmaf( t, apq, A[ut(Q,Q)]);
    A[ut(P,Q)] = 0.0f;
    f32x2 cc = {c, c}, ss = {s, s}, ns = {-s, -s};
    #pragma unroll
    for (int h = 0; h < 3; ++h) {
        f32x2 vp = VC[P][h], vq = VC[Q][h];
        VC[P][h] = pk_fma(cc, vp, pk_mul(ns, vq));
        VC[Q][h] = pk_fma(cc, vq, pk_mul(ss, vp));
    }
}

template<int P0,int Q0,int P1,int Q1,int P2,int Q2>
__device__ __forceinline__ void jround3(float (&A)[21], f32x2 (&VC)[6][3]) {
    float c0,s0,t0,c1,s1,t1,c2,s2,t2;
    jangle<P0,Q0>(A, c0, s0, t0);   // disjoint pivots: 3 independent chains
    jangle<P1,Q1>(A, c1, s1, t1);
    jangle<P2,Q2>(A, c2, s2, t2);
    japply<P0,Q0>(A, VC, c0, s0, t0);
    japply<P1,Q1>(A, VC, c1, s1, t1);
    japply<P2,Q2>(A, VC, c2, s2, t2);
}

__device__ __forceinline__ void jacobi6f(float (&A)[21], f32x2 (&VC)[6][3], int sweeps) {
    #pragma unroll
    for (int j = 0; j < 6; ++j)
        #pragma unroll
        for (int h = 0; h < 3; ++h)
            VC[j][h] = f32x2{(2*h == j) ? 1.0f : 0.0f, (2*h+1 == j) ? 1.0f : 0.0f};
    for (int sw = 0; sw < sweeps; ++sw) {
        jround3<0,5, 1,4, 2,3>(A, VC);
        jround3<0,4, 3,5, 1,2>(A, VC);
        jround3<0,3, 2,4, 1,5>(A, VC);
        jround3<0,2, 1,3, 4,5>(A, VC);
        jround3<0,1, 2,5, 3,4>(A, VC);
    }
}

// ---------------- Schur complement S -> A6 (precision T) -------------------
template<typename T>
__device__ __forceinline__ void schur6(const T (&S)[45], float (&A6)[6][6]) {
    T g00 = S[SIDX(6,6)], g01 = S[SIDX(6,7)], g02 = S[SIDX(6,8)];
    T g11 = S[SIDX(7,7)], g12 = S[SIDX(7,8)], g22 = S[SIDX(8,8)];
    T c00 = g11 * g22 - g12 * g12;
    T c01 = g02 * g12 - g01 * g22;
    T c02 = g01 * g12 - g02 * g11;
    T det = g00 * c00 + g01 * c01 + g02 * c02;
    T invdet = (T)1 / det;
    T gi00 = c00 * invdet, gi01 = c01 * invdet, gi02 = c02 * invdet;
    T gi11 = (g00 * g22 - g02 * g02) * invdet;
    T gi12 = (g01 * g02 - g00 * g12) * invdet;
    T gi22 = (g00 * g11 - g01 * g01) * invdet;

    T B0[6], B1[6], B2[6], T0[6], T1[6], T2[6];
    #pragma unroll
    for (int m = 0; m < 6; ++m) {
        B0[m] = S[SIDX(m,6)]; B1[m] = S[SIDX(m,7)]; B2[m] = S[SIDX(m,8)];
    }
    #pragma unroll
    for (int m = 0; m < 6; ++m) {
        T0[m] = gi00 * B0[m] + gi01 * B1[m] + gi02 * B2[m];
        T1[m] = gi01 * B0[m] + gi11 * B1[m] + gi12 * B2[m];
        T2[m] = gi02 * B0[m] + gi12 * B1[m] + gi22 * B2[m];
    }
    #pragma unroll
    for (int m = 0; m < 6; ++m)
        #pragma unroll
        for (int n = m; n < 6; ++n) {
            T val = S[SIDX(m,n)] - (B0[m] * T0[n] + B1[m] * T1[n] + B2[m] * T2[n]);
            A6[m][n] = (float)val; A6[n][m] = (float)val;
        }
}

// 19 depth-weighted moments, packed over pixel pairs (f32x2 accumulators)
struct Wm {
    float W1_u,W1_v,W1_uu,W1_uv,W1_vv,W1_u3,W1_uuv,W1_uvv,W1_v3;
    float W2_1,W2_u,W2_v,W2_uu,W2_uv,W2_vv;
    float W3_1,W3_u,W3_v,W4_1;
};

__device__ __forceinline__ void accum_moments(const f32x2 (&wvp)[32], Wm& W) {
    const f32x2 CU[4]  = {{-4.f,-3.f},{-2.f,-1.f},{0.f,1.f},{2.f,3.f}};
    const f32x2 CU2[4] = {{16.f,9.f},{4.f,1.f},{0.f,1.f},{4.f,9.f}};
    const f32x2 CU3[4] = {{-64.f,-27.f},{-8.f,-1.f},{0.f,1.f},{8.f,27.f}};
    const f32x2 VB[8]  = {{-4.f,-4.f},{-3.f,-3.f},{-2.f,-2.f},{-1.f,-1.f},{0.f,0.f},{1.f,1.f},{2.f,2.f},{3.f,3.f}};
    const f32x2 V2B[8] = {{16.f,16.f},{9.f,9.f},{4.f,4.f},{1.f,1.f},{0.f,0.f},{1.f,1.f},{4.f,4.f},{9.f,9.f}};
    const f32x2 V3B[8] = {{-64.f,-64.f},{-27.f,-27.f},{-8.f,-8.f},{-1.f,-1.f},{0.f,0.f},{1.f,1.f},{8.f,8.f},{27.f,27.f}};

    f32x2 u={0,0}, v={0,0}, uu={0,0}, uv={0,0}, vv={0,0}, u3={0,0}, uuv={0,0}, uvv={0,0}, v3={0,0};
    f32x2 q1={0,0}, qu={0,0}, qv={0,0}, quu={0,0}, quv={0,0}, qvv={0,0};
    f32x2 c1={0,0}, cu={0,0}, cv={0,0}, h1={0,0};

    #pragma unroll
    for (int r = 0; r < 8; ++r) {
        #pragma unroll
        for (int cp = 0; cp < 4; ++cp) {
            f32x2 wp  = wvp[r*4+cp];
            f32x2 w2p = pk_mul(wp, wp);
            f32x2 w3p = pk_mul(w2p, wp);
            f32x2 uw  = pk_mul(CU[cp], wp);
            f32x2 u2w = pk_mul(CU2[cp], wp);
            f32x2 uw2 = pk_mul(CU[cp], w2p);
            u   = pk_add(u, uw);
            v   = pk_fma(VB[r], wp, v);
            uu  = pk_add(uu, u2w);
            uv  = pk_fma(VB[r], uw, uv);
            vv  = pk_fma(V2B[r], wp, vv);
            u3  = pk_fma(CU3[cp], wp, u3);
            uuv = pk_fma(VB[r], u2w, uuv);
            uvv = pk_fma(V2B[r], uw, uvv);
            v3  = pk_fma(V3B[r], wp, v3);
            q1  = pk_fma(wp, wp, q1);
            qu  = pk_add(qu, uw2);
            qv  = pk_fma(VB[r], w2p, qv);
            quu = pk_fma(CU2[cp], w2p, quu);
            quv = pk_fma(VB[r], uw2, quv);
            qvv = pk_fma(V2B[r], w2p, qvv);
            c1  = pk_add(c1, w3p);
            cu  = pk_fma(CU[cp], w3p, cu);
            cv  = pk_fma(VB[r], w3p, cv);
            h1  = pk_fma(w2p, w2p, h1);
        }
    }
    W.W1_u  = u.x + u.y;    W.W1_v  = v.x + v.y;    W.W1_uu = uu.x + uu.y;
    W.W1_uv = uv.x + uv.y;  W.W1_vv = vv.x + vv.y;  W.W1_u3 = u3.x + u3.y;
    W.W1_uuv= uuv.x + uuv.y;W.W1_uvv= uvv.x + uvv.y;W.W1_v3 = v3.x + v3.y;
    W.W2_1  = q1.x + q1.y;  W.W2_u  = qu.x + qu.y;  W.W2_v  = qv.x + qv.y;
    W.W2_uu = quu.x + quu.y;W.W2_uv = quv.x + quv.y;W.W2_vv = qvv.x + qvv.y;
    W.W3_1  = c1.x + c1.y;  W.W3_u  = cu.x + cu.y;  W.W3_v  = cv.x + cv.y;
    W.W4_1  = h1.x + h1.y;
}

__global__ __launch_bounds__(64, 1)
void curv_kernel(const float* __restrict__ depth, float* __restrict__ out) {
    unsigned k = blockIdx.x * 64u + threadIdx.x;
    if (k >= 16384u) return;

    // Partition: 252 exact waves interior (excl. (127,127)); 4 exact waves
    // boundary + (127,127). No wave mixes the two code paths.
    int pi, pj;
    bool boundary;
    if (k < 16128u) {
        pi = 1 + (int)(k / 127u);
        pj = 1 + (int)(k % 127u);
        boundary = false;
    } else {
        unsigned b = k - 16128u;        // 0..255
        if (b < 128u)      { pi = 0; pj = (int)b; }
        else if (b < 255u) { pi = (int)(b - 127u); pj = 0; }
        else               { pi = 127; pj = 127; }
        boundary = true;
    }

    float A6[6][6];

    if (!boundary) {
        // aligned float4 loads: 3 chunks/row covering cols 8pj-4 .. 8pj+8
        const float* rowbase = depth + (pi * 8 - 1) * IMGW + (pj * 8 - 4);
        float4 F[8][3];
        #pragma unroll
        for (int r = 0; r < 8; ++r) {
            const float4* rp = reinterpret_cast<const float4*>(rowbase + r * IMGW);
            F[r][0] = rp[0]; F[r][1] = rp[1]; F[r][2] = rp[2];
        }
        float d36 = F[4][1].w;           // row 4, col 8pj+3
        f32x2 wvp[32];
        #pragma unroll
        for (int r = 0; r < 8; ++r) {
            wvp[r*4+0] = f32x2{F[r][0].w - d36, F[r][1].x - d36};
            wvp[r*4+1] = f32x2{F[r][1].y - d36, F[r][1].z - d36};
            wvp[r*4+2] = f32x2{F[r][1].w - d36, F[r][2].x - d36};
            wvp[r*4+3] = f32x2{F[r][2].y - d36, F[r][2].z - d36};
        }

        Wm W;
        accum_moments(wvp, W);

        float S[45];
        S[SIDX(0,0)] = 3616.0f;   S[SIDX(0,1)] = 1936.0f;  S[SIDX(0,2)] = W.W2_uu;
        S[SIDX(0,3)] = 512.0f;    S[SIDX(0,4)] = 2.0f*W.W1_u3; S[SIDX(0,5)] = 2.0f*W.W1_uuv;
        S[SIDX(0,6)] = -1024.0f;  S[SIDX(0,7)] = -352.0f;  S[SIDX(0,8)] = 2.0f*W.W1_uu;
        S[SIDX(1,1)] = 3616.0f;   S[SIDX(1,2)] = W.W2_vv;  S[SIDX(1,3)] = 512.0f;
        S[SIDX(1,4)] = 2.0f*W.W1_uvv; S[SIDX(1,5)] = 2.0f*W.W1_v3;
        S[SIDX(1,6)] = -352.0f;   S[SIDX(1,7)] = -1024.0f; S[SIDX(1,8)] = 2.0f*W.W1_vv;
        S[SIDX(2,2)] = W.W4_1;    S[SIDX(2,3)] = 2.0f*W.W2_uv;
        S[SIDX(2,4)] = 2.0f*W.W3_u; S[SIDX(2,5)] = 2.0f*W.W3_v;
        S[SIDX(2,6)] = 2.0f*W.W2_u; S[SIDX(2,7)] = 2.0f*W.W2_v; S[SIDX(2,8)] = 2.0f*W.W3_1;
        S[SIDX(3,3)] = 7744.0f;   S[SIDX(3,4)] = 4.0f*W.W1_uuv; S[SIDX(3,5)] = 4.0f*W.W1_uvv;
        S[SIDX(3,6)] = -704.0f;   S[SIDX(3,7)] = -704.0f;  S[SIDX(3,8)] = 4.0f*W.W1_uv;
        S[SIDX(4,4)] = 4.0f*W.W2_uu; S[SIDX(4,5)] = 4.0f*W.W2_uv;
        S[SIDX(4,6)] = 4.0f*W.W1_uu; S[SIDX(4,7)] = 4.0f*W.W1_uv; S[SIDX(4,8)] = 4.0f*W.W2_u;
        S[SIDX(5,5)] = 4.0f*W.W2_vv;
        S[SIDX(5,6)] = 4.0f*W.W1_uv; S[SIDX(5,7)] = 4.0f*W.W1_vv; S[SIDX(5,8)] = 4.0f*W.W2_v;
        S[SIDX(6,6)] = 1408.0f;   S[SIDX(6,7)] = 64.0f;    S[SIDX(6,8)] = 4.0f*W.W1_u;
        S[SIDX(7,7)] = 1408.0f;   S[SIDX(7,8)] = 4.0f*W.W1_v;
        S[SIDX(8,8)] = 4.0f*W.W2_1;
        schur6<float>(S, A6);
    } else {
        bool top = (pi == 0), left = (pj == 0);
        int pat = (top ? 1 : 0) + (left ? 2 : 0);
        int baseR = pi * 8 - 1, baseC = pj * 8 - 1;
        float d36 = depth[(pi * 8 + 3) * IMGW + (pj * 8 + 3)];
        float wv[64];
        #pragma unroll
        for (int r = 0; r < 8; ++r) {
            int ir = max(baseR + r, 0);
            #pragma unroll
            for (int c = 0; c < 8; ++c) {
                int ic = max(baseC + c, 0);
                wv[r * 8 + c] = depth[ir * IMGW + ic];
            }
        }
        #pragma unroll
        for (int r = 0; r < 8; ++r)
            #pragma unroll
            for (int c = 0; c < 8; ++c) {
                bool pad = (top && r == 0) || (left && c == 0);
                wv[r * 8 + c] = pad ? 0.0f : (wv[r * 8 + c] - d36);
            }
        f32x2 wvp[32];
        #pragma unroll
        for (int i = 0; i < 32; ++i) wvp[i] = f32x2{wv[2*i], wv[2*i+1]};

        Wm W;
        accum_moments(wvp, W);

        const float* P = PURE[pat];
        float S32[45];
        S32[SIDX(0,0)] = P[P_U4];    S32[SIDX(0,1)] = P[P_U2V2]; S32[SIDX(0,2)] = W.W2_uu;
        S32[SIDX(0,3)] = 2.0f*P[P_U3V]; S32[SIDX(0,4)] = 2.0f*W.W1_u3; S32[SIDX(0,5)] = 2.0f*W.W1_uuv;
        S32[SIDX(0,6)] = 2.0f*P[P_U3]; S32[SIDX(0,7)] = 2.0f*P[P_U2V]; S32[SIDX(0,8)] = 2.0f*W.W1_uu;
        S32[SIDX(1,1)] = P[P_V4];    S32[SIDX(1,2)] = W.W2_vv;   S32[SIDX(1,3)] = 2.0f*P[P_UV3];
        S32[SIDX(1,4)] = 2.0f*W.W1_uvv; S32[SIDX(1,5)] = 2.0f*W.W1_v3;
        S32[SIDX(1,6)] = 2.0f*P[P_UV2]; S32[SIDX(1,7)] = 2.0f*P[P_V3]; S32[SIDX(1,8)] = 2.0f*W.W1_vv;
        S32[SIDX(2,2)] = W.W4_1;     S32[SIDX(2,3)] = 2.0f*W.W2_uv;
        S32[SIDX(2,4)] = 2.0f*W.W3_u; S32[SIDX(2,5)] = 2.0f*W.W3_v;
        S32[SIDX(2,6)] = 2.0f*W.W2_u; S32[SIDX(2,7)] = 2.0f*W.W2_v; S32[SIDX(2,8)] = 2.0f*W.W3_1;
        S32[SIDX(3,3)] = 4.0f*P[P_U2V2]; S32[SIDX(3,4)] = 4.0f*W.W1_uuv; S32[SIDX(3,5)] = 4.0f*W.W1_uvv;
        S32[SIDX(3,6)] = 4.0f*P[P_U2V]; S32[SIDX(3,7)] = 4.0f*P[P_UV2]; S32[SIDX(3,8)] = 4.0f*W.W1_uv;
        S32[SIDX(4,4)] = 4.0f*W.W2_uu; S32[SIDX(4,5)] = 4.0f*W.W2_uv;
        S32[SIDX(4,6)] = 4.0f*W.W1_uu; S32[SIDX(4,7)] = 4.0f*W.W1_uv; S32[SIDX(4,8)] = 4.0f*W.W2_u;
        S32[SIDX(5,5)] = 4.0f*W.W2_vv;
        S32[SIDX(5,6)] = 4.0f*W.W1_uv; S32[SIDX(5,7)] = 4.0f*W.W1_vv; S32[SIDX(5,8)] = 4.0f*W.W2_v;
        S32[SIDX(6,6)] = 4.0f*P[P_U2]; S32[SIDX(6,7)] = 4.0f*P[P_UV]; S32[SIDX(6,8)] = 4.0f*W.W1_u;
        S32[SIDX(7,7)] = 4.0f*P[P_V2]; S32[SIDX(7,8)] = 4.0f*W.W1_v;
        S32[SIDX(8,8)] = 4.0f*W.W2_1;

        // exact f64 rank-1 far-point update for the coincident pad pixels
        double m = (double)((top ? 8 : 0) + (left ? 8 : 0) - ((top && left) ? 1 : 0));
        double xf = -(double)(pj * 8 + 3);
        double yf = -(double)(pi * 8 + 3);
        double df = -(double)d36;
        double d9f[9];
        d9f[0] = xf * xf; d9f[1] = yf * yf; d9f[2] = df * df;
        d9f[3] = 2.0 * xf * yf; d9f[4] = 2.0 * xf * df; d9f[5] = 2.0 * yf * df;
        d9f[6] = 2.0 * xf; d9f[7] = 2.0 * yf; d9f[8] = 2.0 * df;
        double S64[45];
        #pragma unroll
        for (int mm = 0; mm < 9; ++mm)
            #pragma unroll
            for (int nn = mm; nn < 9; ++nn)
                S64[SIDX(mm,nn)] = (double)S32[SIDX(mm,nn)] + m * d9f[mm] * d9f[nn];
        schur6<double>(S64, A6);
    }

    // ---- Cholesky A + ridge = L L^T ----
    float tr = A6[0][0] + A6[1][1] + A6[2][2] + A6[3][3] + A6[4][4] + A6[5][5];
    float ridge = 1e-6f * tr + 1e-30f;
    float dfloor = 1e-12f * tr + 1e-30f;
    float L[6][6];
    #pragma unroll
    for (int i = 0; i < 6; ++i)
        #pragma unroll
        for (int j = 0; j < 6; ++j)
            L[i][j] = 0.0f;
    #pragma unroll
    for (int j = 0; j < 6; ++j) {
        float d = A6[j][j] + ridge;
        #pragma unroll
        for (int kk = 0; kk < 6; ++kk)
            if (kk < j) d = fmaf(-L[j][kk], L[j][kk], d);
        d = fmaxf(d, dfloor);
        float sd = sqrtf(d);
        float isd = __builtin_amdgcn_rcpf(sd);
        L[j][j] = sd;
        #pragma unroll
        for (int i = 0; i < 6; ++i) {
            if (i > j) {
                float v = A6[i][j];
                #pragma unroll
                for (int kk = 0; kk < 6; ++kk)
                    if (kk < j) v = fmaf(-L[i][kk], L[j][kk], v);
                L[i][j] = v * isd;
            }
        }
    }

    // ---- Ms = L^T Cinv L (upper-tri storage); Cinv = blockdiag((J-I)/2, -I/4)
    float N[6][6];
    #pragma unroll
    for (int j = 0; j < 6; ++j) {
        N[0][j] = 0.5f * (L[1][j] + L[2][j]);
        N[1][j] = 0.5f * (L[0][j] + L[2][j]);
        N[2][j] = 0.5f * (L[0][j] + L[1][j]);
        N[3][j] = -0.25f * L[3][j];
        N[4][j] = -0.25f * L[4][j];
        N[5][j] = -0.25f * L[5][j];
    }
    float Ms[21];
    #pragma unroll
    for (int i = 0; i < 6; ++i)
        #pragma unroll
        for (int j = 0; j < 6; ++j) {
            if (i <= j) {
                float acc = 0.0f;
                #pragma unroll
                for (int kk = 0; kk < 6; ++kk)
                    acc = fmaf(L[kk][i], N[kk][j], acc);
                Ms[ut(i,j)] = acc;
            }
        }

    // ---- Jacobi (symmetric storage + packed V, 3 sweeps) ----
    f32x2 VC[6][3];
    jacobi6f(Ms, VC, 3);
    float l2max = Ms[ut(0,0)];
    int imax = 0;
    #pragma unroll
    for (int i = 1; i < 6; ++i) {
        float di = Ms[ut(i,i)];
        if (di > l2max) { l2max = di; imax = i; }
    }
    float y6[6];
    #pragma unroll
    for (int i = 0; i < 6; ++i) {
        float acc = 0.0f;
        #pragma unroll
        for (int jj = 0; jj < 6; ++jj) {
            float vij = (i & 1) ? VC[jj][i >> 1].y : VC[jj][i >> 1].x;
            acc += (jj == imax) ? vij : 0.0f;
        }
        y6[i] = acc;
    }

    // ---- v = L^{-T} y (back-substitution) ----
    float v5 = y6[5] * __builtin_amdgcn_rcpf(L[5][5]);
    float v4 = (y6[4] - L[5][4]*v5) * __builtin_amdgcn_rcpf(L[4][4]);
    float v3 = (y6[3] - L[4][3]*v4 - L[5][3]*v5) * __builtin_amdgcn_rcpf(L[3][3]);
    float v2 = (y6[2] - L[3][2]*v3 - L[4][2]*v4 - L[5][2]*v5) * __builtin_amdgcn_rcpf(L[2][2]);
    float v1 = (y6[1] - L[2][1]*v2 - L[3][1]*v3 - L[4][1]*v4 - L[5][1]*v5) * __builtin_amdgcn_rcpf(L[1][1]);
    float v0 = (y6[0] - L[1][0]*v1 - L[2][0]*v2 - L[3][0]*v3 - L[4][0]*v4 - L[5][0]*v5) * __builtin_amdgcn_rcpf(L[0][0]);

    // ---- 3x3 symmetric eigenvalue ratio (closed form, f32) ----
    float a = v0, b = v1, cc = v2, d = v3, e = v4, f = v5;
    float ev0, ev1, ev2;
    float off = d * d + e * e + f * f;
    if (off == 0.0f) {
        ev0 = a; ev1 = b; ev2 = cc;
    } else {
        float q = (a + b + cc) * (1.0f / 3.0f);
        float p2 = (a-q)*(a-q) + (b-q)*(b-q) + (cc-q)*(cc-q) + 2.0f * off;
        float p = sqrtf(p2 * (1.0f / 6.0f));
        float ip = __builtin_amdgcn_rcpf(p);
        float b00 = (a - q) * ip, b11 = (b - q) * ip, b22 = (cc - q) * ip;
        float b01 = d * ip, b02 = e * ip, b12 = f * ip;
        float detB = b00 * (b11 * b22 - b12 * b12)
                   - b01 * (b01 * b22 - b12 * b02)
                   + b02 * (b01 * b12 - b11 * b02);
        float rr = 0.5f * detB;
        rr = fminf(1.0f, fmaxf(-1.0f, rr));
        float phi = acosf(rr) * (1.0f / 3.0f);
        ev0 = q + 2.0f * p * cosf(phi);
        ev2 = q + 2.0f * p * cosf(phi + (float)(2.0 * M_PI / 3.0));
        ev1 = 3.0f * q - ev0 - ev2;
    }
    float A0 = fabsf(ev0), A1 = fabsf(ev1), A2 = fabsf(ev2);
    float mx = fmaxf(A0, fmaxf(A1, A2));
    float mn = fminf(A0, fminf(A1, A2));
    float simi = sqrtf(fmaxf(mn, 1e-9f) / fmaxf(mx, 1e-9f));

    out[pi * 128 + pj] = simi;
}

extern "C" void kernel_launch(void* const* d_in, const int* in_sizes, int n_in,
                              void* d_out, int out_size, void* d_ws, size_t ws_size,
                              hipStream_t stream) {
    const float* depth = (const float*)d_in[0];
    float* out = (float*)d_out;
    curv_kernel<<<dim3(256), dim3(64), 0, stream>>>(depth, out);
}